// Round 1
// baseline (5435.891 us; speedup 1.0000x reference)
//
#include <hip/hip_runtime.h>
#include <math.h>

// ---------------- constants ----------------
// B=8 S=256 D=512 H=8 hd=64 DI=1024 DS=16 DC=4 DTR=32 DF=1024
// rows = B*S = 2048

// ---------------- reduction helpers (blockDim == 256) ----------------
__device__ inline float wave_sum(float v) {
#pragma unroll
  for (int o = 32; o > 0; o >>= 1) v += __shfl_xor(v, o, 64);
  return v;
}
__device__ inline float wave_maxf(float v) {
#pragma unroll
  for (int o = 32; o > 0; o >>= 1) v = fmaxf(v, __shfl_xor(v, o, 64));
  return v;
}
__device__ inline float block_sum(float v, float* sm) {
  v = wave_sum(v);
  if ((threadIdx.x & 63) == 0) sm[threadIdx.x >> 6] = v;
  __syncthreads();
  float r = sm[0] + sm[1] + sm[2] + sm[3];
  __syncthreads();
  return r;
}
__device__ inline float block_max(float v, float* sm) {
  v = wave_maxf(v);
  if ((threadIdx.x & 63) == 0) sm[threadIdx.x >> 6] = v;
  __syncthreads();
  float r = fmaxf(fmaxf(sm[0], sm[1]), fmaxf(sm[2], sm[3]));
  __syncthreads();
  return r;
}

// ---------------- GEMM  C = alpha*(A @ W^T) + bias, act, + res ----------------
// grid: (N/64, M/64, batch). act: 0 none, 1 softplus, 2 relu.
__global__ __launch_bounds__(256) void gemm_tn(
    const float* __restrict__ A, int lda, long long sA,
    const float* __restrict__ W, int ldw, long long sW,
    const float* __restrict__ bias,
    const float* __restrict__ res,
    float* __restrict__ C, int ldc, long long sC,
    int K, float alpha, int act) {
  __shared__ float As[16][68];
  __shared__ float Ws[16][68];
  const int bz = blockIdx.z;
  A += sA * bz; W += sW * bz; C += sC * bz;
  const int m0 = blockIdx.y * 64, n0 = blockIdx.x * 64;
  const int tid = threadIdx.x;
  const int tx = tid & 15, ty = tid >> 4;
  float acc[4][4] = {{0.f}};
  for (int k0 = 0; k0 < K; k0 += 16) {
#pragma unroll
    for (int l = 0; l < 4; ++l) {
      int idx = tid + l * 256;
      int r = idx >> 4, c = idx & 15;
      As[c][r] = A[(long long)(m0 + r) * lda + (k0 + c)];
      Ws[c][r] = W[(long long)(n0 + r) * ldw + (k0 + c)];
    }
    __syncthreads();
#pragma unroll
    for (int kk = 0; kk < 16; ++kk) {
      const float4 a = *(const float4*)&As[kk][ty * 4];
      const float4 b = *(const float4*)&Ws[kk][tx * 4];
      acc[0][0] += a.x * b.x; acc[0][1] += a.x * b.y; acc[0][2] += a.x * b.z; acc[0][3] += a.x * b.w;
      acc[1][0] += a.y * b.x; acc[1][1] += a.y * b.y; acc[1][2] += a.y * b.z; acc[1][3] += a.y * b.w;
      acc[2][0] += a.z * b.x; acc[2][1] += a.z * b.y; acc[2][2] += a.z * b.z; acc[2][3] += a.z * b.w;
      acc[3][0] += a.w * b.x; acc[3][1] += a.w * b.y; acc[3][2] += a.w * b.z; acc[3][3] += a.w * b.w;
    }
    __syncthreads();
  }
  const int mb = m0 + ty * 4, nb = n0 + tx * 4;
  float bja[4] = {0.f, 0.f, 0.f, 0.f};
  if (bias) {
    const float4 bv = *(const float4*)&bias[nb];
    bja[0] = bv.x; bja[1] = bv.y; bja[2] = bv.z; bja[3] = bv.w;
  }
#pragma unroll
  for (int i = 0; i < 4; ++i) {
    long long row = mb + i;
    float vv[4];
#pragma unroll
    for (int j = 0; j < 4; ++j) {
      float v = acc[i][j] * alpha + bja[j];
      if (act == 1) v = fmaxf(v, 0.f) + log1pf(expf(-fabsf(v)));   // softplus
      else if (act == 2) v = fmaxf(v, 0.f);                        // relu
      vv[j] = v;
    }
    float4 o = make_float4(vv[0], vv[1], vv[2], vv[3]);
    if (res) {
      const float4 r4 = *(const float4*)&res[row * ldc + nb];
      o.x += r4.x; o.y += r4.y; o.z += r4.z; o.w += r4.w;
    }
    *(float4*)&C[row * ldc + nb] = o;
  }
}

// ---------------- GEMM  C = A @ B (NN, batched, no epilogue) ----------------
__global__ __launch_bounds__(256) void gemm_nn(
    const float* __restrict__ A, int lda, long long sA,
    const float* __restrict__ B, int ldb, long long sB,
    float* __restrict__ C, int ldc, long long sC, int K) {
  __shared__ float As[16][68];
  __shared__ float Bs[16][68];
  const int bz = blockIdx.z;
  A += sA * bz; B += sB * bz; C += sC * bz;
  const int m0 = blockIdx.y * 64, n0 = blockIdx.x * 64;
  const int tid = threadIdx.x, tx = tid & 15, ty = tid >> 4;
  float acc[4][4] = {{0.f}};
  for (int k0 = 0; k0 < K; k0 += 16) {
#pragma unroll
    for (int l = 0; l < 4; ++l) {
      int idx = tid + l * 256;
      int rA = idx >> 4, cA = idx & 15;
      As[cA][rA] = A[(long long)(m0 + rA) * lda + (k0 + cA)];
      int rB = idx >> 6, cB = idx & 63;
      Bs[rB][cB] = B[(long long)(k0 + rB) * ldb + (n0 + cB)];
    }
    __syncthreads();
#pragma unroll
    for (int kk = 0; kk < 16; ++kk) {
      const float4 a = *(const float4*)&As[kk][ty * 4];
      const float4 b = *(const float4*)&Bs[kk][tx * 4];
      acc[0][0] += a.x * b.x; acc[0][1] += a.x * b.y; acc[0][2] += a.x * b.z; acc[0][3] += a.x * b.w;
      acc[1][0] += a.y * b.x; acc[1][1] += a.y * b.y; acc[1][2] += a.y * b.z; acc[1][3] += a.y * b.w;
      acc[2][0] += a.z * b.x; acc[2][1] += a.z * b.y; acc[2][2] += a.z * b.z; acc[2][3] += a.z * b.w;
      acc[3][0] += a.w * b.x; acc[3][1] += a.w * b.y; acc[3][2] += a.w * b.z; acc[3][3] += a.w * b.w;
    }
    __syncthreads();
  }
  const int mb = m0 + ty * 4, nb = n0 + tx * 4;
#pragma unroll
  for (int i = 0; i < 4; ++i) {
    long long row = mb + i;
    *(float4*)&C[row * ldc + nb] = make_float4(acc[i][0], acc[i][1], acc[i][2], acc[i][3]);
  }
}

// ---------------- LayerNorm (one block per row of 512) ----------------
// mode 0: torch_ln  (biased var, eps=1e-5 inside sqrt)
// mode 1: custom_ln/adaln (unbiased std, eps=1e-6 added to s)
// in2/in3 optional summed residuals. add_pe: add sinusoidal PE (pos = batch idx).
__device__ inline float pe_val(int bi, int c) {
  float f = expf((float)(c & ~1) * (-9.210340371976184f / 512.f)); // -ln(10000)/D
  float arg = (float)bi * f;
  return (c & 1) ? cosf(arg) : sinf(arg);
}
__global__ __launch_bounds__(256) void ln_kernel(
    const float* __restrict__ in1, const float* __restrict__ in2,
    const float* __restrict__ in3, const float* __restrict__ g,
    const float* __restrict__ bb, float* __restrict__ out, int mode, int add_pe) {
  __shared__ float sm[4];
  const int row = blockIdx.x, tid = threadIdx.x;
  const long long base = (long long)row * 512;
  float x0 = in1[base + tid];
  float x1 = in1[base + tid + 256];
  if (in2) { x0 += in2[base + tid]; x1 += in2[base + tid + 256]; }
  if (in3) { x0 += in3[base + tid]; x1 += in3[base + tid + 256]; }
  if (add_pe) {
    int bi = row >> 8;  // row / S
    x0 += pe_val(bi, tid);
    x1 += pe_val(bi, tid + 256);
  }
  float m = block_sum(x0 + x1, sm) * (1.f / 512.f);
  float d0 = x0 - m, d1 = x1 - m;
  float ss = block_sum(d0 * d0 + d1 * d1, sm);
  float r0, r1;
  if (mode == 0) {
    float rstd = rsqrtf(ss * (1.f / 512.f) + 1e-5f);
    r0 = d0 * rstd * g[tid] + bb[tid];
    r1 = d1 * rstd * g[tid + 256] + bb[tid + 256];
  } else {
    float s = sqrtf(ss * (1.f / 511.f));
    float inv = 1.f / (s + 1e-6f);
    r0 = g[tid] * d0 * inv + bb[tid];
    r1 = g[tid + 256] * d1 * inv + bb[tid + 256];
  }
  out[base + tid] = r0;
  out[base + tid + 256] = r1;
}

// ---------------- causal depthwise conv (DC=4) + SiLU ----------------
// u input = xz cols [0,1024), ld 2048. out u2 (B,S,DI).
__global__ __launch_bounds__(256) void conv_silu(
    const float* __restrict__ xz, const float* __restrict__ cw,
    const float* __restrict__ cb, float* __restrict__ u2) {
  int idx = blockIdx.x * 256 + threadIdx.x;           // b*S*DI + t*DI + c
  int c = idx & 1023, t = (idx >> 10) & 255, b = idx >> 18;
  const float* base = xz + (long long)b * 256 * 2048;
  float acc = cb[c];
#pragma unroll
  for (int k = 0; k < 4; ++k) {
    int tt = t + k - 3;
    if (tt >= 0) acc += base[tt * 2048 + c] * cw[c * 4 + k];
  }
  u2[idx] = acc / (1.f + expf(-acc));
}

// ---------------- selective-scan (one thread per (b,d)) ----------------
__global__ __launch_bounds__(256) void scan_kernel(
    const float* __restrict__ delta, const float* __restrict__ u2,
    const float* __restrict__ xz, const float* __restrict__ xdbl,
    const float* __restrict__ Alog, const float* __restrict__ Dp,
    float* __restrict__ ys) {
  const int d = blockIdx.x * 256 + threadIdx.x;  // 0..1023
  const int b = blockIdx.y;
  float A[16], h[16];
#pragma unroll
  for (int s = 0; s < 16; ++s) { A[s] = -expf(Alog[d * 16 + s]); h[s] = 0.f; }
  const float Dd = Dp[d];
  for (int t = 0; t < 256; ++t) {
    const int r = b * 256 + t;
    const float dt = delta[r * 1024 + d];
    const float uu = u2[r * 1024 + d];
    const float zz = xz[(long long)r * 2048 + 1024 + d];
    const float du = dt * uu;
    const float* xd = xdbl + r * 64;
    float y = 0.f;
#pragma unroll
    for (int s = 0; s < 16; ++s) {
      h[s] = expf(dt * A[s]) * h[s] + du * xd[32 + s];
      y += h[s] * xd[48 + s];
    }
    y = (y + Dd * uu) * (zz / (1.f + expf(-zz)));
    ys[r * 1024 + d] = y;
  }
}

// ---------------- softmax over rows of 256 (in place) ----------------
__global__ __launch_bounds__(256) void softmax_rows(float* __restrict__ S) {
  __shared__ float sm[4];
  float* p = S + (long long)blockIdx.x * 256;
  float v = p[threadIdx.x];
  float m = block_max(v, sm);
  float e = expf(v - m);
  float s = block_sum(e, sm);
  p[threadIdx.x] = e / s;
}

// ---------------- head layout transposes ----------------
// (B,S,H*hd) -> (B,H,S,hd)
__global__ __launch_bounds__(256) void to_heads(const float* __restrict__ in, float* __restrict__ out) {
  int idx = blockIdx.x * 256 + threadIdx.x;
  int c = idx & 63, s = (idx >> 6) & 255, h = (idx >> 14) & 7, b = idx >> 17;
  out[idx] = in[(b * 256 + s) * 512 + h * 64 + c];
}
// (B,H,S,hd) -> (B,S,H*hd)
__global__ __launch_bounds__(256) void from_heads(const float* __restrict__ in, float* __restrict__ out) {
  int idx = blockIdx.x * 256 + threadIdx.x;
  int d = idx & 511, s = (idx >> 9) & 255, b = idx >> 17;
  int h = d >> 6, c = d & 63;
  out[idx] = in[((b * 8 + h) * 256 + s) * 64 + c];
}

// ---------------- host orchestration ----------------
extern "C" void kernel_launch(void* const* d_in, const int* in_sizes, int n_in,
                              void* d_out, int out_size, void* d_ws, size_t ws_size,
                              hipStream_t stream) {
  (void)in_sizes; (void)n_in; (void)out_size; (void)ws_size;
  const float* text   = (const float*)d_in[0];
  const float* video  = (const float*)d_in[1];
  const float* audio  = (const float*)d_in[2];
  const float* emb_w  = (const float*)d_in[3];
  const float* emb_b  = (const float*)d_in[4];
  const float* ada_a  = (const float*)d_in[5];
  const float* ada_b  = (const float*)d_in[6];
  const float* m_in_w = (const float*)d_in[7];
  const float* m_cw   = (const float*)d_in[8];
  const float* m_cb   = (const float*)d_in[9];
  const float* m_xp   = (const float*)d_in[10];
  const float* m_dtw  = (const float*)d_in[11];
  const float* m_dtb  = (const float*)d_in[12];
  const float* m_Alog = (const float*)d_in[13];
  const float* m_Dp   = (const float*)d_in[14];
  const float* m_ow   = (const float*)d_in[15];
  const float* m_lng  = (const float*)d_in[16];
  const float* m_lnb  = (const float*)d_in[17];
  const float* qkv_w  = (const float*)d_in[18];
  const float* qkv_b  = (const float*)d_in[19];
  const float* aout_w = (const float*)d_in[20];
  const float* aout_b = (const float*)d_in[21];
  const float* sln_g  = (const float*)d_in[22];
  const float* sln_b  = (const float*)d_in[23];
  const float* f_w1   = (const float*)d_in[24];
  const float* f_b1   = (const float*)d_in[25];
  const float* f_w2   = (const float*)d_in[26];
  const float* f_b2   = (const float*)d_in[27];
  const float* f_lng  = (const float*)d_in[28];
  const float* f_lnb  = (const float*)d_in[29];
  const float* n1_g   = (const float*)d_in[30];
  const float* n1_b   = (const float*)d_in[31];
  float* outp = (float*)d_out;

  // workspace layout (floats)
  float* ws = (float*)d_ws;
  size_t off = 0;
  auto alloc = [&](size_t n) { float* p = ws + off; off += n; return p; };
  float* sb[6];
  for (int i = 0; i < 6; ++i) sb[i] = alloc(2048 * 512);
  float* xz   = alloc(2048 * 2048);   // also: attention scores (B*H*S*S)
  float* u2   = alloc(2048 * 1024);   // also: qh, ffn hidden
  float* dl   = alloc(2048 * 1024);   // also: kh
  float* ysb  = alloc(2048 * 1024);   // also: vh
  float* xdbl = alloc(2048 * 64);
  float* n1bf = alloc(2048 * 512);    // also: oh, mtmp, ffn h2
  float* n2bf = alloc(2048 * 512);    // also: o flat
  float* qbf  = alloc(2048 * 512);
  float* kbf  = alloc(2048 * 512);
  float* vbf  = alloc(2048 * 512);
  float* scores = xz;
  float* qh = u2; float* kh = dl; float* vh = ysb;
  float* oh = n1bf; float* ob = n2bf; float* mtmp = n1bf;
  float* hbuf = u2; float* h2 = n1bf;

  auto gemm = [&](const float* A, int lda, const float* W, int ldw,
                  const float* bias, const float* res, float* C, int ldc,
                  int M, int N, int K, float alpha, int act,
                  int batch, long long sA, long long sW, long long sC) {
    dim3 g(N / 64, M / 64, batch);
    gemm_tn<<<g, 256, 0, stream>>>(A, lda, sA, W, ldw, sW, bias, res, C, ldc, sC, K, alpha, act);
  };
  auto ln = [&](const float* i1, const float* i2, const float* i3,
                const float* g, const float* b, float* o, int mode, int pe) {
    ln_kernel<<<2048, 256, 0, stream>>>(i1, i2, i3, g, b, o, mode, pe);
  };

  auto mamba_layer = [&](float* x, int i) {
    gemm(x, 512, m_in_w + (size_t)i * 2048 * 512, 512, nullptr, nullptr, xz, 2048,
         2048, 2048, 512, 1.f, 0, 1, 0, 0, 0);
    conv_silu<<<8192, 256, 0, stream>>>(xz, m_cw + (size_t)i * 1024 * 4,
                                        m_cb + (size_t)i * 1024, u2);
    gemm(u2, 1024, m_xp + (size_t)i * 64 * 1024, 1024, nullptr, nullptr, xdbl, 64,
         2048, 64, 1024, 1.f, 0, 1, 0, 0, 0);
    gemm(xdbl, 64, m_dtw + (size_t)i * 1024 * 32, 32, m_dtb + (size_t)i * 1024,
         nullptr, dl, 1024, 2048, 1024, 32, 1.f, 1, 1, 0, 0, 0);
    scan_kernel<<<dim3(4, 8), 256, 0, stream>>>(dl, u2, xz, xdbl,
                                                m_Alog + (size_t)i * 1024 * 16,
                                                m_Dp + (size_t)i * 1024, ysb);
    gemm(ysb, 1024, m_ow + (size_t)i * 512 * 1024, 1024, nullptr, nullptr, mtmp, 512,
         2048, 512, 1024, 1.f, 0, 1, 0, 0, 0);
    ln(x, mtmp, nullptr, m_lng + (size_t)i * 512, m_lnb + (size_t)i * 512, x, 0, 0);
  };

  auto sub = [&](const float* s1, const float* s2, int i, float* o_str) {
    ln(s1, nullptr, nullptr, sln_g + (size_t)i * 512, sln_b + (size_t)i * 512, n1bf, 0, 0);
    ln(s2, nullptr, nullptr, sln_g + (size_t)i * 512, sln_b + (size_t)i * 512, n2bf, 0, 0);
    const float* wq = qkv_w + ((size_t)i * 3 + 0) * 512 * 512;
    const float* wk = qkv_w + ((size_t)i * 3 + 1) * 512 * 512;
    const float* wv = qkv_w + ((size_t)i * 3 + 2) * 512 * 512;
    const float* bq = qkv_b + ((size_t)i * 3 + 0) * 512;
    const float* bk = qkv_b + ((size_t)i * 3 + 1) * 512;
    const float* bv = qkv_b + ((size_t)i * 3 + 2) * 512;
    gemm(n1bf, 512, wq, 512, bq, nullptr, qbf, 512, 2048, 512, 512, 1.f, 0, 1, 0, 0, 0);
    gemm(n2bf, 512, wk, 512, bk, nullptr, kbf, 512, 2048, 512, 512, 1.f, 0, 1, 0, 0, 0);
    gemm(n2bf, 512, wv, 512, bv, nullptr, vbf, 512, 2048, 512, 512, 1.f, 0, 1, 0, 0, 0);
    to_heads<<<4096, 256, 0, stream>>>(qbf, qh);
    to_heads<<<4096, 256, 0, stream>>>(kbf, kh);
    to_heads<<<4096, 256, 0, stream>>>(vbf, vh);
    // scores[bh] = (1/8) * Qh @ Kh^T   (M=N=256, K=64, batch=64)
    gemm(qh, 64, kh, 64, nullptr, nullptr, scores, 256, 256, 256, 64, 0.125f, 0,
         64, 16384, 16384, 65536);
    softmax_rows<<<16384, 256, 0, stream>>>(scores);
    // oh[bh] = P @ Vh  (M=256, N=64, K=256)
    gemm_nn<<<dim3(1, 4, 64), 256, 0, stream>>>(scores, 256, 65536LL, vh, 64,
                                                16384LL, oh, 64, 16384LL, 256);
    from_heads<<<4096, 256, 0, stream>>>(oh, ob);
    gemm(ob, 512, aout_w + (size_t)i * 512 * 512, 512, aout_b + (size_t)i * 512,
         s1, o_str, 512, 2048, 512, 512, 1.f, 0, 1, 0, 0, 0);
  };

  auto ffn = [&](float* x, int i) {
    gemm(x, 512, f_w1 + (size_t)i * 1024 * 512, 512, f_b1 + (size_t)i * 1024,
         nullptr, hbuf, 1024, 2048, 1024, 512, 1.f, 2, 1, 0, 0, 0);
    gemm(hbuf, 1024, f_w2 + (size_t)i * 512 * 1024, 1024, f_b2 + (size_t)i * 512,
         nullptr, h2, 512, 2048, 512, 1024, 1.f, 0, 1, 0, 0, 0);
    ln(x, h2, nullptr, f_lng + (size_t)i * 512, f_lnb + (size_t)i * 512, x, 1, 0);
  };

  // ---- stems ----
  const float* ins[3] = {text, video, audio};
  for (int j = 0; j < 3; ++j) {
    gemm(ins[j], 512, emb_w, 512, emb_b, nullptr, sb[j], 512, 2048, 512, 512, 1.f, 0, 1, 0, 0, 0);
    ln(sb[j], nullptr, nullptr, ada_a, ada_b, sb[j], 1, 1);  // +PE, adaln
  }
  // ---- mamba 0..2 ----
  for (int j = 0; j < 3; ++j) mamba_layer(sb[j], j);
  // ---- self attention 0..2 ----
  sub(sb[0], sb[0], 0, sb[3]);
  sub(sb[1], sb[1], 1, sb[4]);
  sub(sb[2], sb[2], 2, sb[5]);
  // ---- cross attention 3..5 (t=sb3, v=sb4, a=sb5) ----
  sub(sb[3], sb[5], 3, sb[0]);
  sub(sb[4], sb[3], 4, sb[1]);
  sub(sb[5], sb[4], 5, sb[2]);
  // ---- mamba 3..5 ----
  for (int j = 0; j < 3; ++j) mamba_layer(sb[j], 3 + j);
  // ---- self attention 6..8 ----
  sub(sb[0], sb[0], 6, sb[3]);
  sub(sb[1], sb[1], 7, sb[4]);
  sub(sb[2], sb[2], 8, sb[5]);
  // ---- ffn 0..2 ----
  for (int j = 0; j < 3; ++j) ffn(sb[3 + j], j);
  // ---- final norm: torch_ln(t+v+a) -> out ----
  ln(sb[3], sb[4], sb[5], n1_g, n1_b, outp, 0, 0);
}

// Round 2
// 4864.942 us; speedup vs baseline: 1.1174x; 1.1174x over previous
//
#include <hip/hip_runtime.h>
#include <math.h>

// ---------------- constants ----------------
// B=8 S=256 D=512 H=8 hd=64 DI=1024 DS=16 DC=4 DTR=32 DF=1024
// rows = B*S = 2048

// ---------------- reduction helpers (blockDim == 256) ----------------
__device__ inline float wave_sum(float v) {
#pragma unroll
  for (int o = 32; o > 0; o >>= 1) v += __shfl_xor(v, o, 64);
  return v;
}
__device__ inline float wave_maxf(float v) {
#pragma unroll
  for (int o = 32; o > 0; o >>= 1) v = fmaxf(v, __shfl_xor(v, o, 64));
  return v;
}
__device__ inline float block_sum(float v, float* sm) {
  v = wave_sum(v);
  if ((threadIdx.x & 63) == 0) sm[threadIdx.x >> 6] = v;
  __syncthreads();
  float r = sm[0] + sm[1] + sm[2] + sm[3];
  __syncthreads();
  return r;
}
__device__ inline float block_max(float v, float* sm) {
  v = wave_maxf(v);
  if ((threadIdx.x & 63) == 0) sm[threadIdx.x >> 6] = v;
  __syncthreads();
  float r = fmaxf(fmaxf(sm[0], sm[1]), fmaxf(sm[2], sm[3]));
  __syncthreads();
  return r;
}

// ---------------- GEMM  C = alpha*(A @ W^T) + bias, act, + res ----------------
// grid: (N/64, M/64, batch). act: 0 none, 1 softplus, 2 relu.
__global__ __launch_bounds__(256) void gemm_tn(
    const float* __restrict__ A, int lda, long long sA,
    const float* __restrict__ W, int ldw, long long sW,
    const float* __restrict__ bias,
    const float* __restrict__ res,
    float* __restrict__ C, int ldc, long long sC,
    int K, float alpha, int act) {
  __shared__ float As[16][68];
  __shared__ float Ws[16][68];
  const int bz = blockIdx.z;
  A += sA * bz; W += sW * bz; C += sC * bz;
  const int m0 = blockIdx.y * 64, n0 = blockIdx.x * 64;
  const int tid = threadIdx.x;
  const int tx = tid & 15, ty = tid >> 4;
  float acc[4][4] = {{0.f}};
  for (int k0 = 0; k0 < K; k0 += 16) {
#pragma unroll
    for (int l = 0; l < 4; ++l) {
      int idx = tid + l * 256;
      int r = idx >> 4, c = idx & 15;
      As[c][r] = A[(long long)(m0 + r) * lda + (k0 + c)];
      Ws[c][r] = W[(long long)(n0 + r) * ldw + (k0 + c)];
    }
    __syncthreads();
#pragma unroll
    for (int kk = 0; kk < 16; ++kk) {
      const float4 a = *(const float4*)&As[kk][ty * 4];
      const float4 b = *(const float4*)&Ws[kk][tx * 4];
      acc[0][0] += a.x * b.x; acc[0][1] += a.x * b.y; acc[0][2] += a.x * b.z; acc[0][3] += a.x * b.w;
      acc[1][0] += a.y * b.x; acc[1][1] += a.y * b.y; acc[1][2] += a.y * b.z; acc[1][3] += a.y * b.w;
      acc[2][0] += a.z * b.x; acc[2][1] += a.z * b.y; acc[2][2] += a.z * b.z; acc[2][3] += a.z * b.w;
      acc[3][0] += a.w * b.x; acc[3][1] += a.w * b.y; acc[3][2] += a.w * b.z; acc[3][3] += a.w * b.w;
    }
    __syncthreads();
  }
  const int mb = m0 + ty * 4, nb = n0 + tx * 4;
  float bja[4] = {0.f, 0.f, 0.f, 0.f};
  if (bias) {
    const float4 bv = *(const float4*)&bias[nb];
    bja[0] = bv.x; bja[1] = bv.y; bja[2] = bv.z; bja[3] = bv.w;
  }
#pragma unroll
  for (int i = 0; i < 4; ++i) {
    long long row = mb + i;
    float vv[4];
#pragma unroll
    for (int j = 0; j < 4; ++j) {
      float v = acc[i][j] * alpha + bja[j];
      if (act == 1) v = fmaxf(v, 0.f) + log1pf(expf(-fabsf(v)));   // softplus
      else if (act == 2) v = fmaxf(v, 0.f);                        // relu
      vv[j] = v;
    }
    float4 o = make_float4(vv[0], vv[1], vv[2], vv[3]);
    if (res) {
      const float4 r4 = *(const float4*)&res[row * ldc + nb];
      o.x += r4.x; o.y += r4.y; o.z += r4.z; o.w += r4.w;
    }
    *(float4*)&C[row * ldc + nb] = o;
  }
}

// ---------------- GEMM  C = A @ B (NN, batched, no epilogue) ----------------
__global__ __launch_bounds__(256) void gemm_nn(
    const float* __restrict__ A, int lda, long long sA,
    const float* __restrict__ B, int ldb, long long sB,
    float* __restrict__ C, int ldc, long long sC, int K) {
  __shared__ float As[16][68];
  __shared__ float Bs[16][68];
  const int bz = blockIdx.z;
  A += sA * bz; B += sB * bz; C += sC * bz;
  const int m0 = blockIdx.y * 64, n0 = blockIdx.x * 64;
  const int tid = threadIdx.x, tx = tid & 15, ty = tid >> 4;
  float acc[4][4] = {{0.f}};
  for (int k0 = 0; k0 < K; k0 += 16) {
#pragma unroll
    for (int l = 0; l < 4; ++l) {
      int idx = tid + l * 256;
      int rA = idx >> 4, cA = idx & 15;
      As[cA][rA] = A[(long long)(m0 + rA) * lda + (k0 + cA)];
      int rB = idx >> 6, cB = idx & 63;
      Bs[rB][cB] = B[(long long)(k0 + rB) * ldb + (n0 + cB)];
    }
    __syncthreads();
#pragma unroll
    for (int kk = 0; kk < 16; ++kk) {
      const float4 a = *(const float4*)&As[kk][ty * 4];
      const float4 b = *(const float4*)&Bs[kk][tx * 4];
      acc[0][0] += a.x * b.x; acc[0][1] += a.x * b.y; acc[0][2] += a.x * b.z; acc[0][3] += a.x * b.w;
      acc[1][0] += a.y * b.x; acc[1][1] += a.y * b.y; acc[1][2] += a.y * b.z; acc[1][3] += a.y * b.w;
      acc[2][0] += a.z * b.x; acc[2][1] += a.z * b.y; acc[2][2] += a.z * b.z; acc[2][3] += a.z * b.w;
      acc[3][0] += a.w * b.x; acc[3][1] += a.w * b.y; acc[3][2] += a.w * b.z; acc[3][3] += a.w * b.w;
    }
    __syncthreads();
  }
  const int mb = m0 + ty * 4, nb = n0 + tx * 4;
#pragma unroll
  for (int i = 0; i < 4; ++i) {
    long long row = mb + i;
    *(float4*)&C[row * ldc + nb] = make_float4(acc[i][0], acc[i][1], acc[i][2], acc[i][3]);
  }
}

// ---------------- LayerNorm (one block per row of 512) ----------------
// mode 0: torch_ln  (biased var, eps=1e-5 inside sqrt)
// mode 1: custom_ln/adaln (unbiased std, eps=1e-6 added to s)
// in2/in3 optional summed residuals. add_pe: add sinusoidal PE (pos = batch idx).
__device__ inline float pe_val(int bi, int c) {
  float f = expf((float)(c & ~1) * (-9.210340371976184f / 512.f)); // -ln(10000)/D
  float arg = (float)bi * f;
  return (c & 1) ? cosf(arg) : sinf(arg);
}
__global__ __launch_bounds__(256) void ln_kernel(
    const float* __restrict__ in1, const float* __restrict__ in2,
    const float* __restrict__ in3, const float* __restrict__ g,
    const float* __restrict__ bb, float* __restrict__ out, int mode, int add_pe) {
  __shared__ float sm[4];
  const int row = blockIdx.x, tid = threadIdx.x;
  const long long base = (long long)row * 512;
  float x0 = in1[base + tid];
  float x1 = in1[base + tid + 256];
  if (in2) { x0 += in2[base + tid]; x1 += in2[base + tid + 256]; }
  if (in3) { x0 += in3[base + tid]; x1 += in3[base + tid + 256]; }
  if (add_pe) {
    int bi = row >> 8;  // row / S
    x0 += pe_val(bi, tid);
    x1 += pe_val(bi, tid + 256);
  }
  float m = block_sum(x0 + x1, sm) * (1.f / 512.f);
  float d0 = x0 - m, d1 = x1 - m;
  float ss = block_sum(d0 * d0 + d1 * d1, sm);
  float r0, r1;
  if (mode == 0) {
    float rstd = rsqrtf(ss * (1.f / 512.f) + 1e-5f);
    r0 = d0 * rstd * g[tid] + bb[tid];
    r1 = d1 * rstd * g[tid + 256] + bb[tid + 256];
  } else {
    float s = sqrtf(ss * (1.f / 511.f));
    float inv = 1.f / (s + 1e-6f);
    r0 = g[tid] * d0 * inv + bb[tid];
    r1 = g[tid + 256] * d1 * inv + bb[tid + 256];
  }
  out[base + tid] = r0;
  out[base + tid + 256] = r1;
}

// ---------------- causal depthwise conv (DC=4) + SiLU ----------------
// u input = xz cols [0,1024), ld 2048. out u2 (B,S,DI).
__global__ __launch_bounds__(256) void conv_silu(
    const float* __restrict__ xz, const float* __restrict__ cw,
    const float* __restrict__ cb, float* __restrict__ u2) {
  int idx = blockIdx.x * 256 + threadIdx.x;           // b*S*DI + t*DI + c
  int c = idx & 1023, t = (idx >> 10) & 255, b = idx >> 18;
  const float* base = xz + (long long)b * 256 * 2048;
  float acc = cb[c];
#pragma unroll
  for (int k = 0; k < 4; ++k) {
    int tt = t + k - 3;
    if (tt >= 0) acc += base[tt * 2048 + c] * cw[c * 4 + k];
  }
  u2[idx] = acc / (1.f + expf(-acc));
}

// ---------------- selective-scan, lane-per-(d,s) ----------------
// wave = 4 d-values x 16 states: s = lane>>2, dsub = lane&3.
// Serial chain is one FMA/step; exp(dt*A) is h-independent (pipelines).
// grid: (64, 8) x 256 threads -> 2048 waves (8 waves/CU).
__global__ __launch_bounds__(256) void scan_kernel(
    const float* __restrict__ delta, const float* __restrict__ u2,
    const float* __restrict__ xz, const float* __restrict__ xdbl,
    const float* __restrict__ Alog, const float* __restrict__ Dp,
    float* __restrict__ ys) {
  const int lane = threadIdx.x & 63;
  const int wv = threadIdx.x >> 6;            // 0..3
  const int s = lane >> 2;                    // 0..15
  const int dsub = lane & 3;
  const int d = blockIdx.x * 16 + wv * 4 + dsub;  // 0..1023
  const int b = blockIdx.y;
  const float A = -expf(Alog[d * 16 + s]);
  const float Dd = Dp[d];
  const float* __restrict__ dlt = delta + (long long)b * 256 * 1024 + d;
  const float* __restrict__ uu2 = u2 + (long long)b * 256 * 1024 + d;
  const float* __restrict__ zzp = xz + (long long)b * 256 * 2048 + 1024 + d;
  const float* __restrict__ xd = xdbl + (long long)b * 256 * 64;
  float* __restrict__ yo = ys + (long long)b * 256 * 1024 + d;
  float h = 0.f;
#pragma unroll 4
  for (int t = 0; t < 256; ++t) {
    const float dt = dlt[t * 1024];
    const float uu = uu2[t * 1024];
    const float Bs = xd[t * 64 + 32 + s];
    const float Cs = xd[t * 64 + 48 + s];
    h = __expf(dt * A) * h + dt * uu * Bs;
    float p = h * Cs;
    p += __shfl_xor(p, 4, 64);
    p += __shfl_xor(p, 8, 64);
    p += __shfl_xor(p, 16, 64);
    p += __shfl_xor(p, 32, 64);
    if (s == 0) {
      const float zz = zzp[t * 2048];
      yo[t * 1024] = (p + Dd * uu) * (zz / (1.f + expf(-zz)));
    }
  }
}

// ---------------- softmax over rows of 256 (in place) ----------------
__global__ __launch_bounds__(256) void softmax_rows(float* __restrict__ S) {
  __shared__ float sm[4];
  float* p = S + (long long)blockIdx.x * 256;
  float v = p[threadIdx.x];
  float m = block_max(v, sm);
  float e = expf(v - m);
  float s = block_sum(e, sm);
  p[threadIdx.x] = e / s;
}

// ---------------- head layout transposes ----------------
// (B,S,H*hd) -> (B,H,S,hd)
__global__ __launch_bounds__(256) void to_heads(const float* __restrict__ in, float* __restrict__ out) {
  int idx = blockIdx.x * 256 + threadIdx.x;
  int c = idx & 63, s = (idx >> 6) & 255, h = (idx >> 14) & 7, b = idx >> 17;
  out[idx] = in[(b * 256 + s) * 512 + h * 64 + c];
}
// (B,H,S,hd) -> (B,S,H*hd)
__global__ __launch_bounds__(256) void from_heads(const float* __restrict__ in, float* __restrict__ out) {
  int idx = blockIdx.x * 256 + threadIdx.x;
  int d = idx & 511, s = (idx >> 9) & 255, b = idx >> 17;
  int h = d >> 6, c = d & 63;
  out[idx] = in[((b * 8 + h) * 256 + s) * 64 + c];
}

// ---------------- host orchestration ----------------
extern "C" void kernel_launch(void* const* d_in, const int* in_sizes, int n_in,
                              void* d_out, int out_size, void* d_ws, size_t ws_size,
                              hipStream_t stream) {
  (void)in_sizes; (void)n_in; (void)out_size; (void)ws_size;
  const float* text   = (const float*)d_in[0];
  const float* video  = (const float*)d_in[1];
  const float* audio  = (const float*)d_in[2];
  const float* emb_w  = (const float*)d_in[3];
  const float* emb_b  = (const float*)d_in[4];
  const float* ada_a  = (const float*)d_in[5];
  const float* ada_b  = (const float*)d_in[6];
  const float* m_in_w = (const float*)d_in[7];
  const float* m_cw   = (const float*)d_in[8];
  const float* m_cb   = (const float*)d_in[9];
  const float* m_xp   = (const float*)d_in[10];
  const float* m_dtw  = (const float*)d_in[11];
  const float* m_dtb  = (const float*)d_in[12];
  const float* m_Alog = (const float*)d_in[13];
  const float* m_Dp   = (const float*)d_in[14];
  const float* m_ow   = (const float*)d_in[15];
  const float* m_lng  = (const float*)d_in[16];
  const float* m_lnb  = (const float*)d_in[17];
  const float* qkv_w  = (const float*)d_in[18];
  const float* qkv_b  = (const float*)d_in[19];
  const float* aout_w = (const float*)d_in[20];
  const float* aout_b = (const float*)d_in[21];
  const float* sln_g  = (const float*)d_in[22];
  const float* sln_b  = (const float*)d_in[23];
  const float* f_w1   = (const float*)d_in[24];
  const float* f_b1   = (const float*)d_in[25];
  const float* f_w2   = (const float*)d_in[26];
  const float* f_b2   = (const float*)d_in[27];
  const float* f_lng  = (const float*)d_in[28];
  const float* f_lnb  = (const float*)d_in[29];
  const float* n1_g   = (const float*)d_in[30];
  const float* n1_b   = (const float*)d_in[31];
  float* outp = (float*)d_out;

  // workspace layout (floats)
  float* ws = (float*)d_ws;
  size_t off = 0;
  auto alloc = [&](size_t n) { float* p = ws + off; off += n; return p; };
  float* sb[6];
  for (int i = 0; i < 6; ++i) sb[i] = alloc(2048 * 512);
  float* xz   = alloc(2048 * 2048);   // also: attention scores (B*H*S*S)
  float* u2   = alloc(2048 * 1024);   // also: qh, ffn hidden
  float* dl   = alloc(2048 * 1024);   // also: kh
  float* ysb  = alloc(2048 * 1024);   // also: vh
  float* xdbl = alloc(2048 * 64);
  float* n1bf = alloc(2048 * 512);    // also: oh, mtmp, ffn h2
  float* n2bf = alloc(2048 * 512);    // also: o flat
  float* qbf  = alloc(2048 * 512);
  float* kbf  = alloc(2048 * 512);
  float* vbf  = alloc(2048 * 512);
  float* scores = xz;
  float* qh = u2; float* kh = dl; float* vh = ysb;
  float* oh = n1bf; float* ob = n2bf; float* mtmp = n1bf;
  float* hbuf = u2; float* h2 = n1bf;

  auto gemm = [&](const float* A, int lda, const float* W, int ldw,
                  const float* bias, const float* res, float* C, int ldc,
                  int M, int N, int K, float alpha, int act,
                  int batch, long long sA, long long sW, long long sC) {
    dim3 g(N / 64, M / 64, batch);
    gemm_tn<<<g, 256, 0, stream>>>(A, lda, sA, W, ldw, sW, bias, res, C, ldc, sC, K, alpha, act);
  };
  auto ln = [&](const float* i1, const float* i2, const float* i3,
                const float* g, const float* b, float* o, int mode, int pe) {
    ln_kernel<<<2048, 256, 0, stream>>>(i1, i2, i3, g, b, o, mode, pe);
  };

  auto mamba_layer = [&](float* x, int i) {
    gemm(x, 512, m_in_w + (size_t)i * 2048 * 512, 512, nullptr, nullptr, xz, 2048,
         2048, 2048, 512, 1.f, 0, 1, 0, 0, 0);
    conv_silu<<<8192, 256, 0, stream>>>(xz, m_cw + (size_t)i * 1024 * 4,
                                        m_cb + (size_t)i * 1024, u2);
    gemm(u2, 1024, m_xp + (size_t)i * 64 * 1024, 1024, nullptr, nullptr, xdbl, 64,
         2048, 64, 1024, 1.f, 0, 1, 0, 0, 0);
    gemm(xdbl, 64, m_dtw + (size_t)i * 1024 * 32, 32, m_dtb + (size_t)i * 1024,
         nullptr, dl, 1024, 2048, 1024, 32, 1.f, 1, 1, 0, 0, 0);
    scan_kernel<<<dim3(64, 8), 256, 0, stream>>>(dl, u2, xz, xdbl,
                                                 m_Alog + (size_t)i * 1024 * 16,
                                                 m_Dp + (size_t)i * 1024, ysb);
    gemm(ysb, 1024, m_ow + (size_t)i * 512 * 1024, 1024, nullptr, nullptr, mtmp, 512,
         2048, 512, 1024, 1.f, 0, 1, 0, 0, 0);
    ln(x, mtmp, nullptr, m_lng + (size_t)i * 512, m_lnb + (size_t)i * 512, x, 0, 0);
  };

  auto sub = [&](const float* s1, const float* s2, int i, float* o_str) {
    ln(s1, nullptr, nullptr, sln_g + (size_t)i * 512, sln_b + (size_t)i * 512, n1bf, 0, 0);
    ln(s2, nullptr, nullptr, sln_g + (size_t)i * 512, sln_b + (size_t)i * 512, n2bf, 0, 0);
    const float* wq = qkv_w + ((size_t)i * 3 + 0) * 512 * 512;
    const float* wk = qkv_w + ((size_t)i * 3 + 1) * 512 * 512;
    const float* wv = qkv_w + ((size_t)i * 3 + 2) * 512 * 512;
    const float* bq = qkv_b + ((size_t)i * 3 + 0) * 512;
    const float* bk = qkv_b + ((size_t)i * 3 + 1) * 512;
    const float* bv = qkv_b + ((size_t)i * 3 + 2) * 512;
    gemm(n1bf, 512, wq, 512, bq, nullptr, qbf, 512, 2048, 512, 512, 1.f, 0, 1, 0, 0, 0);
    gemm(n2bf, 512, wk, 512, bk, nullptr, kbf, 512, 2048, 512, 512, 1.f, 0, 1, 0, 0, 0);
    gemm(n2bf, 512, wv, 512, bv, nullptr, vbf, 512, 2048, 512, 512, 1.f, 0, 1, 0, 0, 0);
    to_heads<<<4096, 256, 0, stream>>>(qbf, qh);
    to_heads<<<4096, 256, 0, stream>>>(kbf, kh);
    to_heads<<<4096, 256, 0, stream>>>(vbf, vh);
    // scores[bh] = (1/8) * Qh @ Kh^T   (M=N=256, K=64, batch=64)
    gemm(qh, 64, kh, 64, nullptr, nullptr, scores, 256, 256, 256, 64, 0.125f, 0,
         64, 16384, 16384, 65536);
    softmax_rows<<<16384, 256, 0, stream>>>(scores);
    // oh[bh] = P @ Vh  (M=256, N=64, K=256)
    gemm_nn<<<dim3(1, 4, 64), 256, 0, stream>>>(scores, 256, 65536LL, vh, 64,
                                                16384LL, oh, 64, 16384LL, 256);
    from_heads<<<4096, 256, 0, stream>>>(oh, ob);
    gemm(ob, 512, aout_w + (size_t)i * 512 * 512, 512, aout_b + (size_t)i * 512,
         s1, o_str, 512, 2048, 512, 512, 1.f, 0, 1, 0, 0, 0);
  };

  auto ffn = [&](float* x, int i) {
    gemm(x, 512, f_w1 + (size_t)i * 1024 * 512, 512, f_b1 + (size_t)i * 1024,
         nullptr, hbuf, 1024, 2048, 1024, 512, 1.f, 2, 1, 0, 0, 0);
    gemm(hbuf, 1024, f_w2 + (size_t)i * 512 * 1024, 1024, f_b2 + (size_t)i * 512,
         nullptr, h2, 512, 2048, 512, 1024, 1.f, 0, 1, 0, 0, 0);
    ln(x, h2, nullptr, f_lng + (size_t)i * 512, f_lnb + (size_t)i * 512, x, 1, 0);
  };

  // ---- stems ----
  const float* ins[3] = {text, video, audio};
  for (int j = 0; j < 3; ++j) {
    gemm(ins[j], 512, emb_w, 512, emb_b, nullptr, sb[j], 512, 2048, 512, 512, 1.f, 0, 1, 0, 0, 0);
    ln(sb[j], nullptr, nullptr, ada_a, ada_b, sb[j], 1, 1);  // +PE, adaln
  }
  // ---- mamba 0..2 ----
  for (int j = 0; j < 3; ++j) mamba_layer(sb[j], j);
  // ---- self attention 0..2 ----
  sub(sb[0], sb[0], 0, sb[3]);
  sub(sb[1], sb[1], 1, sb[4]);
  sub(sb[2], sb[2], 2, sb[5]);
  // ---- cross attention 3..5 (t=sb3, v=sb4, a=sb5) ----
  sub(sb[3], sb[5], 3, sb[0]);
  sub(sb[4], sb[3], 4, sb[1]);
  sub(sb[5], sb[4], 5, sb[2]);
  // ---- mamba 3..5 ----
  for (int j = 0; j < 3; ++j) mamba_layer(sb[j], 3 + j);
  // ---- self attention 6..8 ----
  sub(sb[0], sb[0], 6, sb[3]);
  sub(sb[1], sb[1], 7, sb[4]);
  sub(sb[2], sb[2], 8, sb[5]);
  // ---- ffn 0..2 ----
  for (int j = 0; j < 3; ++j) ffn(sb[3 + j], j);
  // ---- final norm: torch_ln(t+v+a) -> out ----
  ln(sb[3], sb[4], sb[5], n1_g, n1_b, outp, 0, 0);
}

// Round 3
// 4246.214 us; speedup vs baseline: 1.2802x; 1.1457x over previous
//
#include <hip/hip_runtime.h>
#include <math.h>

// ---------------- constants ----------------
// B=8 S=256 D=512 H=8 hd=64 DI=1024 DS=16 DC=4 DTR=32 DF=1024
// rows = B*S = 2048

// ---------------- reduction helpers (blockDim == 256) ----------------
__device__ inline float wave_sum(float v) {
#pragma unroll
  for (int o = 32; o > 0; o >>= 1) v += __shfl_xor(v, o, 64);
  return v;
}
__device__ inline float wave_maxf(float v) {
#pragma unroll
  for (int o = 32; o > 0; o >>= 1) v = fmaxf(v, __shfl_xor(v, o, 64));
  return v;
}
__device__ inline float block_sum(float v, float* sm) {
  v = wave_sum(v);
  if ((threadIdx.x & 63) == 0) sm[threadIdx.x >> 6] = v;
  __syncthreads();
  float r = sm[0] + sm[1] + sm[2] + sm[3];
  __syncthreads();
  return r;
}
__device__ inline float block_max(float v, float* sm) {
  v = wave_maxf(v);
  if ((threadIdx.x & 63) == 0) sm[threadIdx.x >> 6] = v;
  __syncthreads();
  float r = fmaxf(fmaxf(sm[0], sm[1]), fmaxf(sm[2], sm[3]));
  __syncthreads();
  return r;
}

// ---------------- GEMM  C = alpha*(A @ W^T) + bias, act, + res ----------------
// grid: (N/64, M/64, batch). act: 0 none, 1 softplus, 2 relu.
__global__ __launch_bounds__(256) void gemm_tn(
    const float* __restrict__ A, int lda, long long sA,
    const float* __restrict__ W, int ldw, long long sW,
    const float* __restrict__ bias,
    const float* __restrict__ res,
    float* __restrict__ C, int ldc, long long sC,
    int K, float alpha, int act) {
  __shared__ float As[16][68];
  __shared__ float Ws[16][68];
  const int bz = blockIdx.z;
  A += sA * bz; W += sW * bz; C += sC * bz;
  const int m0 = blockIdx.y * 64, n0 = blockIdx.x * 64;
  const int tid = threadIdx.x;
  const int tx = tid & 15, ty = tid >> 4;
  float acc[4][4] = {{0.f}};
  for (int k0 = 0; k0 < K; k0 += 16) {
#pragma unroll
    for (int l = 0; l < 4; ++l) {
      int idx = tid + l * 256;
      int r = idx >> 4, c = idx & 15;
      As[c][r] = A[(long long)(m0 + r) * lda + (k0 + c)];
      Ws[c][r] = W[(long long)(n0 + r) * ldw + (k0 + c)];
    }
    __syncthreads();
#pragma unroll
    for (int kk = 0; kk < 16; ++kk) {
      const float4 a = *(const float4*)&As[kk][ty * 4];
      const float4 b = *(const float4*)&Ws[kk][tx * 4];
      acc[0][0] += a.x * b.x; acc[0][1] += a.x * b.y; acc[0][2] += a.x * b.z; acc[0][3] += a.x * b.w;
      acc[1][0] += a.y * b.x; acc[1][1] += a.y * b.y; acc[1][2] += a.y * b.z; acc[1][3] += a.y * b.w;
      acc[2][0] += a.z * b.x; acc[2][1] += a.z * b.y; acc[2][2] += a.z * b.z; acc[2][3] += a.z * b.w;
      acc[3][0] += a.w * b.x; acc[3][1] += a.w * b.y; acc[3][2] += a.w * b.z; acc[3][3] += a.w * b.w;
    }
    __syncthreads();
  }
  const int mb = m0 + ty * 4, nb = n0 + tx * 4;
  float bja[4] = {0.f, 0.f, 0.f, 0.f};
  if (bias) {
    const float4 bv = *(const float4*)&bias[nb];
    bja[0] = bv.x; bja[1] = bv.y; bja[2] = bv.z; bja[3] = bv.w;
  }
#pragma unroll
  for (int i = 0; i < 4; ++i) {
    long long row = mb + i;
    float vv[4];
#pragma unroll
    for (int j = 0; j < 4; ++j) {
      float v = acc[i][j] * alpha + bja[j];
      if (act == 1) v = fmaxf(v, 0.f) + log1pf(expf(-fabsf(v)));   // softplus
      else if (act == 2) v = fmaxf(v, 0.f);                        // relu
      vv[j] = v;
    }
    float4 o = make_float4(vv[0], vv[1], vv[2], vv[3]);
    if (res) {
      const float4 r4 = *(const float4*)&res[row * ldc + nb];
      o.x += r4.x; o.y += r4.y; o.z += r4.z; o.w += r4.w;
    }
    *(float4*)&C[row * ldc + nb] = o;
  }
}

// ---------------- GEMM  C = A @ B (NN, batched, no epilogue) ----------------
__global__ __launch_bounds__(256) void gemm_nn(
    const float* __restrict__ A, int lda, long long sA,
    const float* __restrict__ B, int ldb, long long sB,
    float* __restrict__ C, int ldc, long long sC, int K) {
  __shared__ float As[16][68];
  __shared__ float Bs[16][68];
  const int bz = blockIdx.z;
  A += sA * bz; B += sB * bz; C += sC * bz;
  const int m0 = blockIdx.y * 64, n0 = blockIdx.x * 64;
  const int tid = threadIdx.x, tx = tid & 15, ty = tid >> 4;
  float acc[4][4] = {{0.f}};
  for (int k0 = 0; k0 < K; k0 += 16) {
#pragma unroll
    for (int l = 0; l < 4; ++l) {
      int idx = tid + l * 256;
      int rA = idx >> 4, cA = idx & 15;
      As[cA][rA] = A[(long long)(m0 + rA) * lda + (k0 + cA)];
      int rB = idx >> 6, cB = idx & 63;
      Bs[rB][cB] = B[(long long)(k0 + rB) * ldb + (n0 + cB)];
    }
    __syncthreads();
#pragma unroll
    for (int kk = 0; kk < 16; ++kk) {
      const float4 a = *(const float4*)&As[kk][ty * 4];
      const float4 b = *(const float4*)&Bs[kk][tx * 4];
      acc[0][0] += a.x * b.x; acc[0][1] += a.x * b.y; acc[0][2] += a.x * b.z; acc[0][3] += a.x * b.w;
      acc[1][0] += a.y * b.x; acc[1][1] += a.y * b.y; acc[1][2] += a.y * b.z; acc[1][3] += a.y * b.w;
      acc[2][0] += a.z * b.x; acc[2][1] += a.z * b.y; acc[2][2] += a.z * b.z; acc[2][3] += a.z * b.w;
      acc[3][0] += a.w * b.x; acc[3][1] += a.w * b.y; acc[3][2] += a.w * b.z; acc[3][3] += a.w * b.w;
    }
    __syncthreads();
  }
  const int mb = m0 + ty * 4, nb = n0 + tx * 4;
#pragma unroll
  for (int i = 0; i < 4; ++i) {
    long long row = mb + i;
    *(float4*)&C[row * ldc + nb] = make_float4(acc[i][0], acc[i][1], acc[i][2], acc[i][3]);
  }
}

// ---------------- LayerNorm (one block per row of 512) ----------------
// mode 0: torch_ln  (biased var, eps=1e-5 inside sqrt)
// mode 1: custom_ln/adaln (unbiased std, eps=1e-6 added to s)
// in2/in3 optional summed residuals. add_pe: add sinusoidal PE (pos = batch idx).
__device__ inline float pe_val(int bi, int c) {
  float f = expf((float)(c & ~1) * (-9.210340371976184f / 512.f)); // -ln(10000)/D
  float arg = (float)bi * f;
  return (c & 1) ? cosf(arg) : sinf(arg);
}
__global__ __launch_bounds__(256) void ln_kernel(
    const float* __restrict__ in1, const float* __restrict__ in2,
    const float* __restrict__ in3, const float* __restrict__ g,
    const float* __restrict__ bb, float* __restrict__ out, int mode, int add_pe) {
  __shared__ float sm[4];
  const int row = blockIdx.x, tid = threadIdx.x;
  const long long base = (long long)row * 512;
  float x0 = in1[base + tid];
  float x1 = in1[base + tid + 256];
  if (in2) { x0 += in2[base + tid]; x1 += in2[base + tid + 256]; }
  if (in3) { x0 += in3[base + tid]; x1 += in3[base + tid + 256]; }
  if (add_pe) {
    int bi = row >> 8;  // row / S
    x0 += pe_val(bi, tid);
    x1 += pe_val(bi, tid + 256);
  }
  float m = block_sum(x0 + x1, sm) * (1.f / 512.f);
  float d0 = x0 - m, d1 = x1 - m;
  float ss = block_sum(d0 * d0 + d1 * d1, sm);
  float r0, r1;
  if (mode == 0) {
    float rstd = rsqrtf(ss * (1.f / 512.f) + 1e-5f);
    r0 = d0 * rstd * g[tid] + bb[tid];
    r1 = d1 * rstd * g[tid + 256] + bb[tid + 256];
  } else {
    float s = sqrtf(ss * (1.f / 511.f));
    float inv = 1.f / (s + 1e-6f);
    r0 = g[tid] * d0 * inv + bb[tid];
    r1 = g[tid + 256] * d1 * inv + bb[tid + 256];
  }
  out[base + tid] = r0;
  out[base + tid + 256] = r1;
}

// ---------------- causal depthwise conv (DC=4) + SiLU ----------------
__global__ __launch_bounds__(256) void conv_silu(
    const float* __restrict__ xz, const float* __restrict__ cw,
    const float* __restrict__ cb, float* __restrict__ u2) {
  int idx = blockIdx.x * 256 + threadIdx.x;           // b*S*DI + t*DI + c
  int c = idx & 1023, t = (idx >> 10) & 255, b = idx >> 18;
  const float* base = xz + (long long)b * 256 * 2048;
  float acc = cb[c];
#pragma unroll
  for (int k = 0; k < 4; ++k) {
    int tt = t + k - 3;
    if (tt >= 0) acc += base[tt * 2048 + c] * cw[c * 4 + k];
  }
  u2[idx] = acc / (1.f + expf(-acc));
}

// ---------------- selective-scan, LDS-staged ----------------
// Block = (b, 16-d tile), 4 waves. Wave lane: s = lane>>2, dsub = lane&3,
// d_local = wv*4+dsub. Per 64-t chunk: cooperative coalesced load of
// delta/u/z (64x16) and xdbl B/C (64x32) into LDS; serial recurrence reads
// LDS (broadcast, conflict-free); y staged in LDS, flushed coalesced.
__global__ __launch_bounds__(256) void scan_kernel(
    const float* __restrict__ delta, const float* __restrict__ u2,
    const float* __restrict__ xz, const float* __restrict__ xdbl,
    const float* __restrict__ Alog, const float* __restrict__ Dp,
    float* __restrict__ ys) {
  __shared__ float sdel[64][16];
  __shared__ float su[64][16];
  __shared__ float sz[64][16];
  __shared__ float sxd[64][32];
  __shared__ float sy[64][16];
  const int tid = threadIdx.x;
  const int lane = tid & 63;
  const int wv = tid >> 6;                 // 0..3
  const int s = lane >> 2;                 // 0..15
  const int dsub = lane & 3;
  const int dl = wv * 4 + dsub;            // 0..15
  const int d0 = blockIdx.x * 16;
  const int d = d0 + dl;
  const int b = blockIdx.y;
  const float A = -expf(Alog[d * 16 + s]);
  const float Dd = Dp[d];
  const long long rowbase = (long long)b * 256;
  float h = 0.f;
  for (int c = 0; c < 4; ++c) {
    const int t0 = c * 64;
    // ---- cooperative load ----
#pragma unroll
    for (int k = 0; k < 4; ++k) {
      int e = k * 256 + tid;               // 0..1023
      int t = e >> 4, dd = e & 15;
      long long r = (rowbase + t0 + t);
      sdel[t][dd] = delta[r * 1024 + d0 + dd];
      su[t][dd]   = u2[r * 1024 + d0 + dd];
      sz[t][dd]   = xz[r * 2048 + 1024 + d0 + dd];
    }
#pragma unroll
    for (int k = 0; k < 8; ++k) {
      int e = k * 256 + tid;               // 0..2047
      int t = e >> 5, j = e & 31;
      sxd[t][j] = xdbl[(rowbase + t0 + t) * 64 + 32 + j];
    }
    __syncthreads();
    // ---- serial recurrence over chunk ----
#pragma unroll 4
    for (int t = 0; t < 64; ++t) {
      const float dt = sdel[t][dl];
      const float uu = su[t][dl];
      const float Bs = sxd[t][s];
      const float Cs = sxd[t][16 + s];
      h = __expf(dt * A) * h + dt * uu * Bs;
      float p = h * Cs;
      p += __shfl_xor(p, 4, 64);
      p += __shfl_xor(p, 8, 64);
      p += __shfl_xor(p, 16, 64);
      p += __shfl_xor(p, 32, 64);
      if (s == 0) {
        const float zz = sz[t][dl];
        sy[t][dl] = (p + Dd * uu) * (zz / (1.f + expf(-zz)));
      }
    }
    __syncthreads();
    // ---- coalesced writeback ----
#pragma unroll
    for (int k = 0; k < 4; ++k) {
      int e = k * 256 + tid;
      int t = e >> 4, dd = e & 15;
      ys[(rowbase + t0 + t) * 1024 + d0 + dd] = sy[t][dd];
    }
  }
}

// ---------------- softmax over rows of 256 (in place) ----------------
__global__ __launch_bounds__(256) void softmax_rows(float* __restrict__ S) {
  __shared__ float sm[4];
  float* p = S + (long long)blockIdx.x * 256;
  float v = p[threadIdx.x];
  float m = block_max(v, sm);
  float e = expf(v - m);
  float s = block_sum(e, sm);
  p[threadIdx.x] = e / s;
}

// ---------------- head layout transposes ----------------
// (B,S,H*hd) -> (B,H,S,hd)
__global__ __launch_bounds__(256) void to_heads(const float* __restrict__ in, float* __restrict__ out) {
  int idx = blockIdx.x * 256 + threadIdx.x;
  int c = idx & 63, s = (idx >> 6) & 255, h = (idx >> 14) & 7, b = idx >> 17;
  out[idx] = in[(b * 256 + s) * 512 + h * 64 + c];
}
// (B,H,S,hd) -> (B,S,H*hd)
__global__ __launch_bounds__(256) void from_heads(const float* __restrict__ in, float* __restrict__ out) {
  int idx = blockIdx.x * 256 + threadIdx.x;
  int d = idx & 511, s = (idx >> 9) & 255, b = idx >> 17;
  int h = d >> 6, c = d & 63;
  out[idx] = in[((b * 8 + h) * 256 + s) * 64 + c];
}

// ---------------- host orchestration ----------------
extern "C" void kernel_launch(void* const* d_in, const int* in_sizes, int n_in,
                              void* d_out, int out_size, void* d_ws, size_t ws_size,
                              hipStream_t stream) {
  (void)in_sizes; (void)n_in; (void)out_size; (void)ws_size;
  const float* text   = (const float*)d_in[0];
  const float* video  = (const float*)d_in[1];
  const float* audio  = (const float*)d_in[2];
  const float* emb_w  = (const float*)d_in[3];
  const float* emb_b  = (const float*)d_in[4];
  const float* ada_a  = (const float*)d_in[5];
  const float* ada_b  = (const float*)d_in[6];
  const float* m_in_w = (const float*)d_in[7];
  const float* m_cw   = (const float*)d_in[8];
  const float* m_cb   = (const float*)d_in[9];
  const float* m_xp   = (const float*)d_in[10];
  const float* m_dtw  = (const float*)d_in[11];
  const float* m_dtb  = (const float*)d_in[12];
  const float* m_Alog = (const float*)d_in[13];
  const float* m_Dp   = (const float*)d_in[14];
  const float* m_ow   = (const float*)d_in[15];
  const float* m_lng  = (const float*)d_in[16];
  const float* m_lnb  = (const float*)d_in[17];
  const float* qkv_w  = (const float*)d_in[18];
  const float* qkv_b  = (const float*)d_in[19];
  const float* aout_w = (const float*)d_in[20];
  const float* aout_b = (const float*)d_in[21];
  const float* sln_g  = (const float*)d_in[22];
  const float* sln_b  = (const float*)d_in[23];
  const float* f_w1   = (const float*)d_in[24];
  const float* f_b1   = (const float*)d_in[25];
  const float* f_w2   = (const float*)d_in[26];
  const float* f_b2   = (const float*)d_in[27];
  const float* f_lng  = (const float*)d_in[28];
  const float* f_lnb  = (const float*)d_in[29];
  const float* n1_g   = (const float*)d_in[30];
  const float* n1_b   = (const float*)d_in[31];
  float* outp = (float*)d_out;

  // workspace layout (floats)
  float* ws = (float*)d_ws;
  size_t off = 0;
  auto alloc = [&](size_t n) { float* p = ws + off; off += n; return p; };
  float* sb[6];
  for (int i = 0; i < 6; ++i) sb[i] = alloc(2048 * 512);
  float* xz   = alloc(2048 * 2048);   // also: attention scores (B*H*S*S)
  float* u2   = alloc(2048 * 1024);   // also: qh, ffn hidden
  float* dl   = alloc(2048 * 1024);   // also: kh
  float* ysb  = alloc(2048 * 1024);   // also: vh
  float* xdbl = alloc(2048 * 64);
  float* n1bf = alloc(2048 * 512);    // also: oh, mtmp, ffn h2
  float* n2bf = alloc(2048 * 512);    // also: o flat
  float* qbf  = alloc(2048 * 512);
  float* kbf  = alloc(2048 * 512);
  float* vbf  = alloc(2048 * 512);
  float* scores = xz;
  float* qh = u2; float* kh = dl; float* vh = ysb;
  float* oh = n1bf; float* ob = n2bf; float* mtmp = n1bf;
  float* hbuf = u2; float* h2 = n1bf;

  auto gemm = [&](const float* A, int lda, const float* W, int ldw,
                  const float* bias, const float* res, float* C, int ldc,
                  int M, int N, int K, float alpha, int act,
                  int batch, long long sA, long long sW, long long sC) {
    dim3 g(N / 64, M / 64, batch);
    gemm_tn<<<g, 256, 0, stream>>>(A, lda, sA, W, ldw, sW, bias, res, C, ldc, sC, K, alpha, act);
  };
  auto ln = [&](const float* i1, const float* i2, const float* i3,
                const float* g, const float* b, float* o, int mode, int pe) {
    ln_kernel<<<2048, 256, 0, stream>>>(i1, i2, i3, g, b, o, mode, pe);
  };

  auto mamba_layer = [&](float* x, int i) {
    gemm(x, 512, m_in_w + (size_t)i * 2048 * 512, 512, nullptr, nullptr, xz, 2048,
         2048, 2048, 512, 1.f, 0, 1, 0, 0, 0);
    conv_silu<<<8192, 256, 0, stream>>>(xz, m_cw + (size_t)i * 1024 * 4,
                                        m_cb + (size_t)i * 1024, u2);
    gemm(u2, 1024, m_xp + (size_t)i * 64 * 1024, 1024, nullptr, nullptr, xdbl, 64,
         2048, 64, 1024, 1.f, 0, 1, 0, 0, 0);
    gemm(xdbl, 64, m_dtw + (size_t)i * 1024 * 32, 32, m_dtb + (size_t)i * 1024,
         nullptr, dl, 1024, 2048, 1024, 32, 1.f, 1, 1, 0, 0, 0);
    scan_kernel<<<dim3(64, 8), 256, 0, stream>>>(dl, u2, xz, xdbl,
                                                 m_Alog + (size_t)i * 1024 * 16,
                                                 m_Dp + (size_t)i * 1024, ysb);
    gemm(ysb, 1024, m_ow + (size_t)i * 512 * 1024, 1024, nullptr, nullptr, mtmp, 512,
         2048, 512, 1024, 1.f, 0, 1, 0, 0, 0);
    ln(x, mtmp, nullptr, m_lng + (size_t)i * 512, m_lnb + (size_t)i * 512, x, 0, 0);
  };

  auto sub = [&](const float* s1, const float* s2, int i, float* o_str) {
    ln(s1, nullptr, nullptr, sln_g + (size_t)i * 512, sln_b + (size_t)i * 512, n1bf, 0, 0);
    ln(s2, nullptr, nullptr, sln_g + (size_t)i * 512, sln_b + (size_t)i * 512, n2bf, 0, 0);
    const float* wq = qkv_w + ((size_t)i * 3 + 0) * 512 * 512;
    const float* wk = qkv_w + ((size_t)i * 3 + 1) * 512 * 512;
    const float* wv = qkv_w + ((size_t)i * 3 + 2) * 512 * 512;
    const float* bq = qkv_b + ((size_t)i * 3 + 0) * 512;
    const float* bk = qkv_b + ((size_t)i * 3 + 1) * 512;
    const float* bv = qkv_b + ((size_t)i * 3 + 2) * 512;
    gemm(n1bf, 512, wq, 512, bq, nullptr, qbf, 512, 2048, 512, 512, 1.f, 0, 1, 0, 0, 0);
    gemm(n2bf, 512, wk, 512, bk, nullptr, kbf, 512, 2048, 512, 512, 1.f, 0, 1, 0, 0, 0);
    gemm(n2bf, 512, wv, 512, bv, nullptr, vbf, 512, 2048, 512, 512, 1.f, 0, 1, 0, 0, 0);
    to_heads<<<4096, 256, 0, stream>>>(qbf, qh);
    to_heads<<<4096, 256, 0, stream>>>(kbf, kh);
    to_heads<<<4096, 256, 0, stream>>>(vbf, vh);
    // scores[bh] = (1/8) * Qh @ Kh^T   (M=N=256, K=64, batch=64)
    gemm(qh, 64, kh, 64, nullptr, nullptr, scores, 256, 256, 256, 64, 0.125f, 0,
         64, 16384, 16384, 65536);
    softmax_rows<<<16384, 256, 0, stream>>>(scores);
    // oh[bh] = P @ Vh  (M=256, N=64, K=256)
    gemm_nn<<<dim3(1, 4, 64), 256, 0, stream>>>(scores, 256, 65536LL, vh, 64,
                                                16384LL, oh, 64, 16384LL, 256);
    from_heads<<<4096, 256, 0, stream>>>(oh, ob);
    gemm(ob, 512, aout_w + (size_t)i * 512 * 512, 512, aout_b + (size_t)i * 512,
         s1, o_str, 512, 2048, 512, 512, 1.f, 0, 1, 0, 0, 0);
  };

  auto ffn = [&](float* x, int i) {
    gemm(x, 512, f_w1 + (size_t)i * 1024 * 512, 512, f_b1 + (size_t)i * 1024,
         nullptr, hbuf, 1024, 2048, 1024, 512, 1.f, 2, 1, 0, 0, 0);
    gemm(hbuf, 1024, f_w2 + (size_t)i * 512 * 1024, 1024, f_b2 + (size_t)i * 512,
         nullptr, h2, 512, 2048, 512, 1024, 1.f, 0, 1, 0, 0, 0);
    ln(x, h2, nullptr, f_lng + (size_t)i * 512, f_lnb + (size_t)i * 512, x, 1, 0);
  };

  // ---- stems ----
  const float* ins[3] = {text, video, audio};
  for (int j = 0; j < 3; ++j) {
    gemm(ins[j], 512, emb_w, 512, emb_b, nullptr, sb[j], 512, 2048, 512, 512, 1.f, 0, 1, 0, 0, 0);
    ln(sb[j], nullptr, nullptr, ada_a, ada_b, sb[j], 1, 1);  // +PE, adaln
  }
  // ---- mamba 0..2 ----
  for (int j = 0; j < 3; ++j) mamba_layer(sb[j], j);
  // ---- self attention 0..2 ----
  sub(sb[0], sb[0], 0, sb[3]);
  sub(sb[1], sb[1], 1, sb[4]);
  sub(sb[2], sb[2], 2, sb[5]);
  // ---- cross attention 3..5 (t=sb3, v=sb4, a=sb5) ----
  sub(sb[3], sb[5], 3, sb[0]);
  sub(sb[4], sb[3], 4, sb[1]);
  sub(sb[5], sb[4], 5, sb[2]);
  // ---- mamba 3..5 ----
  for (int j = 0; j < 3; ++j) mamba_layer(sb[j], 3 + j);
  // ---- self attention 6..8 ----
  sub(sb[0], sb[0], 6, sb[3]);
  sub(sb[1], sb[1], 7, sb[4]);
  sub(sb[2], sb[2], 8, sb[5]);
  // ---- ffn 0..2 ----
  for (int j = 0; j < 3; ++j) ffn(sb[3 + j], j);
  // ---- final norm: torch_ln(t+v+a) -> out ----
  ln(sb[3], sb[4], sb[5], n1_g, n1_b, outp, 0, 0);
}

// Round 4
// 2634.684 us; speedup vs baseline: 2.0632x; 1.6117x over previous
//
#include <hip/hip_runtime.h>
#include <hip/hip_bf16.h>
#include <math.h>

// ---------------- constants ----------------
// B=8 S=256 D=512 H=8 hd=64 DI=1024 DS=16 DC=4 DTR=32 DF=1024
// rows = B*S = 2048

using bf16x8 = __attribute__((ext_vector_type(8))) short;
using floatx16 = __attribute__((ext_vector_type(16))) float;

__device__ inline short2 f2bf2(float x, float y) {
  __hip_bfloat162 h = __float22bfloat162_rn(make_float2(x, y));
  return *reinterpret_cast<short2*>(&h);
}

// ---------------- reduction helpers (blockDim == 256) ----------------
__device__ inline float wave_sum(float v) {
#pragma unroll
  for (int o = 32; o > 0; o >>= 1) v += __shfl_xor(v, o, 64);
  return v;
}
__device__ inline float wave_maxf(float v) {
#pragma unroll
  for (int o = 32; o > 0; o >>= 1) v = fmaxf(v, __shfl_xor(v, o, 64));
  return v;
}
__device__ inline float block_sum(float v, float* sm) {
  v = wave_sum(v);
  if ((threadIdx.x & 63) == 0) sm[threadIdx.x >> 6] = v;
  __syncthreads();
  float r = sm[0] + sm[1] + sm[2] + sm[3];
  __syncthreads();
  return r;
}
__device__ inline float block_max(float v, float* sm) {
  v = wave_maxf(v);
  if ((threadIdx.x & 63) == 0) sm[threadIdx.x >> 6] = v;
  __syncthreads();
  float r = fmaxf(fmaxf(sm[0], sm[1]), fmaxf(sm[2], sm[3]));
  __syncthreads();
  return r;
}

// ---------------- bf16 MFMA GEMM  C = alpha*(A @ W^T) + bias, act, + res ----
// A: M x K f32 (row-major, lda). W: N x K f32 (row-major, ldw). f32 accumulate.
// grid (N/64, M/64, batch). 4 waves: quadrant mq=(wv&1)*32, nq=(wv>>1)*32.
// act: 0 none, 1 softplus, 2 relu.
// omode: 0 plain (idx=m*ldc+n, res usable), 1 heads ((b,s,h*64+c)->(b,h,s,c)),
//        2 unheads (batched bz=b*8+h; write flat (b,s,h*64+c)); pass sC=0.
// LDS frag layout: frag(kg,m) at short offset kg*528 + m*8 (kg stride 1056 B
// = 8 banks) -> staged writes and mfma reads both hit all 32 banks per phase.
__global__ __launch_bounds__(256) void gemm_bf16(
    const float* __restrict__ A, int lda, long long sA,
    const float* __restrict__ W, int ldw, long long sW,
    const float* __restrict__ bias, const float* __restrict__ res,
    float* __restrict__ C, int ldc, long long sC,
    int K, float alpha, int act, int omode) {
  __shared__ short As[4 * 528];
  __shared__ short Bs[4 * 528];
  const int bz = blockIdx.z;
  A += sA * bz; W += sW * bz; C += sC * bz;
  const int m0 = blockIdx.y * 64, n0 = blockIdx.x * 64;
  const int tid = threadIdx.x, lane = tid & 63, wv = tid >> 6;
  const int mq = (wv & 1) * 32, nq = (wv >> 1) * 32;
  const int r31 = lane & 31, half = lane >> 5;
  const int mA = tid >> 2, kgA = tid & 3;   // staging: kg fast -> 128B segs
  floatx16 acc = {};
  const float* pa = A + (long long)(m0 + mA) * lda + kgA * 8;
  const float* pb = W + (long long)(n0 + mA) * ldw + kgA * 8;
  short* wa = As + kgA * 528 + mA * 8;
  short* wb = Bs + kgA * 528 + mA * 8;
  const short* ra = As + (mq + r31) * 8 + half * 528;
  const short* rb = Bs + (nq + r31) * 8 + half * 528;
  for (int k0 = 0; k0 < K; k0 += 32) {
    const float4 a0 = *(const float4*)(pa + k0);
    const float4 a1 = *(const float4*)(pa + k0 + 4);
    const float4 b0 = *(const float4*)(pb + k0);
    const float4 b1 = *(const float4*)(pb + k0 + 4);
    __syncthreads();  // previous iter's frag reads done
    short ta[8], tb[8];
    *(short2*)&ta[0] = f2bf2(a0.x, a0.y); *(short2*)&ta[2] = f2bf2(a0.z, a0.w);
    *(short2*)&ta[4] = f2bf2(a1.x, a1.y); *(short2*)&ta[6] = f2bf2(a1.z, a1.w);
    *(short2*)&tb[0] = f2bf2(b0.x, b0.y); *(short2*)&tb[2] = f2bf2(b0.z, b0.w);
    *(short2*)&tb[4] = f2bf2(b1.x, b1.y); *(short2*)&tb[6] = f2bf2(b1.z, b1.w);
    *(bf16x8*)wa = *(bf16x8*)ta;
    *(bf16x8*)wb = *(bf16x8*)tb;
    __syncthreads();
    // kg = half for k 0..15, kg = 2+half for k 16..31
    acc = __builtin_amdgcn_mfma_f32_32x32x16_bf16(
        *(const bf16x8*)ra, *(const bf16x8*)rb, acc, 0, 0, 0);
    acc = __builtin_amdgcn_mfma_f32_32x32x16_bf16(
        *(const bf16x8*)(ra + 2 * 528), *(const bf16x8*)(rb + 2 * 528), acc, 0, 0, 0);
  }
  const int n = n0 + nq + r31;
  const float bv = bias ? bias[n] : 0.f;
#pragma unroll
  for (int r = 0; r < 16; ++r) {
    const int m = m0 + mq + (r & 3) + 8 * (r >> 2) + 4 * half;
    float v = acc[r] * alpha + bv;
    if (act == 1) v = fmaxf(v, 0.f) + log1pf(expf(-fabsf(v)));
    else if (act == 2) v = fmaxf(v, 0.f);
    if (res) v += res[(long long)m * ldc + n];
    long long idx;
    if (omode == 0) idx = (long long)m * ldc + n;
    else if (omode == 1)
      idx = (long long)(m >> 8) * 131072 + (long long)(n >> 6) * 16384 +
            (m & 255) * 64 + (n & 63);
    else
      idx = (long long)(bz >> 3) * 131072 + (bz & 7) * 64 +
            (long long)m * 512 + n;
    C[idx] = v;
  }
}

// ---------------- LayerNorm (one block per row of 512) ----------------
// mode 0: torch_ln  (biased var, eps=1e-5 inside sqrt)
// mode 1: custom_ln/adaln (unbiased std, eps=1e-6 added to s)
__device__ inline float pe_val(int bi, int c) {
  float f = expf((float)(c & ~1) * (-9.210340371976184f / 512.f)); // -ln(10000)/D
  float arg = (float)bi * f;
  return (c & 1) ? cosf(arg) : sinf(arg);
}
__global__ __launch_bounds__(256) void ln_kernel(
    const float* __restrict__ in1, const float* __restrict__ in2,
    const float* __restrict__ in3, const float* __restrict__ g,
    const float* __restrict__ bb, float* __restrict__ out, int mode, int add_pe) {
  __shared__ float sm[4];
  const int row = blockIdx.x, tid = threadIdx.x;
  const long long base = (long long)row * 512;
  float x0 = in1[base + tid];
  float x1 = in1[base + tid + 256];
  if (in2) { x0 += in2[base + tid]; x1 += in2[base + tid + 256]; }
  if (in3) { x0 += in3[base + tid]; x1 += in3[base + tid + 256]; }
  if (add_pe) {
    int bi = row >> 8;  // row / S
    x0 += pe_val(bi, tid);
    x1 += pe_val(bi, tid + 256);
  }
  float m = block_sum(x0 + x1, sm) * (1.f / 512.f);
  float d0 = x0 - m, d1 = x1 - m;
  float ss = block_sum(d0 * d0 + d1 * d1, sm);
  float r0, r1;
  if (mode == 0) {
    float rstd = rsqrtf(ss * (1.f / 512.f) + 1e-5f);
    r0 = d0 * rstd * g[tid] + bb[tid];
    r1 = d1 * rstd * g[tid + 256] + bb[tid + 256];
  } else {
    float s = sqrtf(ss * (1.f / 511.f));
    float inv = 1.f / (s + 1e-6f);
    r0 = g[tid] * d0 * inv + bb[tid];
    r1 = g[tid + 256] * d1 * inv + bb[tid + 256];
  }
  out[base + tid] = r0;
  out[base + tid + 256] = r1;
}

// ---------------- causal depthwise conv (DC=4) + SiLU ----------------
__global__ __launch_bounds__(256) void conv_silu(
    const float* __restrict__ xz, const float* __restrict__ cw,
    const float* __restrict__ cb, float* __restrict__ u2) {
  int idx = blockIdx.x * 256 + threadIdx.x;           // b*S*DI + t*DI + c
  int c = idx & 1023, t = (idx >> 10) & 255, b = idx >> 18;
  const float* base = xz + (long long)b * 256 * 2048;
  float acc = cb[c];
#pragma unroll
  for (int k = 0; k < 4; ++k) {
    int tt = t + k - 3;
    if (tt >= 0) acc += base[tt * 2048 + c] * cw[c * 4 + k];
  }
  u2[idx] = acc / (1.f + expf(-acc));
}

// ---------------- selective-scan, LDS-staged ----------------
__global__ __launch_bounds__(256) void scan_kernel(
    const float* __restrict__ delta, const float* __restrict__ u2,
    const float* __restrict__ xz, const float* __restrict__ xdbl,
    const float* __restrict__ Alog, const float* __restrict__ Dp,
    float* __restrict__ ys) {
  __shared__ float sdel[64][16];
  __shared__ float su[64][16];
  __shared__ float sz[64][16];
  __shared__ float sxd[64][32];
  __shared__ float sy[64][16];
  const int tid = threadIdx.x;
  const int lane = tid & 63;
  const int wv = tid >> 6;                 // 0..3
  const int s = lane >> 2;                 // 0..15
  const int dsub = lane & 3;
  const int dl = wv * 4 + dsub;            // 0..15
  const int d0 = blockIdx.x * 16;
  const int d = d0 + dl;
  const int b = blockIdx.y;
  const float A = -expf(Alog[d * 16 + s]);
  const float Dd = Dp[d];
  const long long rowbase = (long long)b * 256;
  float h = 0.f;
  for (int c = 0; c < 4; ++c) {
    const int t0 = c * 64;
#pragma unroll
    for (int k = 0; k < 4; ++k) {
      int e = k * 256 + tid;               // 0..1023
      int t = e >> 4, dd = e & 15;
      long long r = (rowbase + t0 + t);
      sdel[t][dd] = delta[r * 1024 + d0 + dd];
      su[t][dd]   = u2[r * 1024 + d0 + dd];
      sz[t][dd]   = xz[r * 2048 + 1024 + d0 + dd];
    }
#pragma unroll
    for (int k = 0; k < 8; ++k) {
      int e = k * 256 + tid;               // 0..2047
      int t = e >> 5, j = e & 31;
      sxd[t][j] = xdbl[(rowbase + t0 + t) * 64 + 32 + j];
    }
    __syncthreads();
#pragma unroll 4
    for (int t = 0; t < 64; ++t) {
      const float dt = sdel[t][dl];
      const float uu = su[t][dl];
      const float Bs = sxd[t][s];
      const float Cs = sxd[t][16 + s];
      h = __expf(dt * A) * h + dt * uu * Bs;
      float p = h * Cs;
      p += __shfl_xor(p, 4, 64);
      p += __shfl_xor(p, 8, 64);
      p += __shfl_xor(p, 16, 64);
      p += __shfl_xor(p, 32, 64);
      if (s == 0) {
        const float zz = sz[t][dl];
        sy[t][dl] = (p + Dd * uu) * (zz / (1.f + expf(-zz)));
      }
    }
    __syncthreads();
#pragma unroll
    for (int k = 0; k < 4; ++k) {
      int e = k * 256 + tid;
      int t = e >> 4, dd = e & 15;
      ys[(rowbase + t0 + t) * 1024 + d0 + dd] = sy[t][dd];
    }
  }
}

// ---------------- softmax over rows of 256 (in place) ----------------
__global__ __launch_bounds__(256) void softmax_rows(float* __restrict__ S) {
  __shared__ float sm[4];
  float* p = S + (long long)blockIdx.x * 256;
  float v = p[threadIdx.x];
  float m = block_max(v, sm);
  float e = expf(v - m);
  float s = block_sum(e, sm);
  p[threadIdx.x] = e / s;
}

// ---------------- V transpose: (B,S,H*hd) -> (B,H,hd,S) ----------------
__global__ __launch_bounds__(256) void to_heads_t(const float* __restrict__ in,
                                                  float* __restrict__ out) {
  int idx = blockIdx.x * 256 + threadIdx.x;
  int s = idx & 255, c = (idx >> 8) & 63, h = (idx >> 14) & 7, b = idx >> 17;
  out[idx] = in[((b * 256 + s) * 512) + h * 64 + c];
}

// ---------------- host orchestration ----------------
extern "C" void kernel_launch(void* const* d_in, const int* in_sizes, int n_in,
                              void* d_out, int out_size, void* d_ws, size_t ws_size,
                              hipStream_t stream) {
  (void)in_sizes; (void)n_in; (void)out_size; (void)ws_size;
  const float* text   = (const float*)d_in[0];
  const float* video  = (const float*)d_in[1];
  const float* audio  = (const float*)d_in[2];
  const float* emb_w  = (const float*)d_in[3];
  const float* emb_b  = (const float*)d_in[4];
  const float* ada_a  = (const float*)d_in[5];
  const float* ada_b  = (const float*)d_in[6];
  const float* m_in_w = (const float*)d_in[7];
  const float* m_cw   = (const float*)d_in[8];
  const float* m_cb   = (const float*)d_in[9];
  const float* m_xp   = (const float*)d_in[10];
  const float* m_dtw  = (const float*)d_in[11];
  const float* m_dtb  = (const float*)d_in[12];
  const float* m_Alog = (const float*)d_in[13];
  const float* m_Dp   = (const float*)d_in[14];
  const float* m_ow   = (const float*)d_in[15];
  const float* m_lng  = (const float*)d_in[16];
  const float* m_lnb  = (const float*)d_in[17];
  const float* qkv_w  = (const float*)d_in[18];
  const float* qkv_b  = (const float*)d_in[19];
  const float* aout_w = (const float*)d_in[20];
  const float* aout_b = (const float*)d_in[21];
  const float* sln_g  = (const float*)d_in[22];
  const float* sln_b  = (const float*)d_in[23];
  const float* f_w1   = (const float*)d_in[24];
  const float* f_b1   = (const float*)d_in[25];
  const float* f_w2   = (const float*)d_in[26];
  const float* f_b2   = (const float*)d_in[27];
  const float* f_lng  = (const float*)d_in[28];
  const float* f_lnb  = (const float*)d_in[29];
  const float* n1_g   = (const float*)d_in[30];
  const float* n1_b   = (const float*)d_in[31];
  float* outp = (float*)d_out;

  // workspace layout (floats)
  float* ws = (float*)d_ws;
  size_t off = 0;
  auto alloc = [&](size_t n) { float* p = ws + off; off += n; return p; };
  float* sb[6];
  for (int i = 0; i < 6; ++i) sb[i] = alloc(2048 * 512);
  float* xz   = alloc(2048 * 2048);   // also: attention scores (B*H*S*S)
  float* u2   = alloc(2048 * 1024);   // also: qh, ffn hidden
  float* dl   = alloc(2048 * 1024);   // also: kh
  float* ysb  = alloc(2048 * 1024);   // also: vt
  float* xdbl = alloc(2048 * 64);
  float* n1bf = alloc(2048 * 512);    // also: mtmp, ffn h2
  float* n2bf = alloc(2048 * 512);    // also: ob (PV output, flat)
  float* vbf  = alloc(2048 * 512);
  float* scores = xz;
  float* qh = u2; float* kh = dl; float* vt = ysb;
  float* ob = n2bf; float* mtmp = n1bf;
  float* hbuf = u2; float* h2 = n1bf;

  auto gemm = [&](const float* A, int lda, long long sA2,
                  const float* W, int ldw, long long sW2,
                  const float* bias, const float* res, float* C, int ldc,
                  long long sC2, int M, int N, int K, float alpha, int act,
                  int omode, int batch) {
    dim3 g(N / 64, M / 64, batch);
    gemm_bf16<<<g, 256, 0, stream>>>(A, lda, sA2, W, ldw, sW2, bias, res, C,
                                     ldc, sC2, K, alpha, act, omode);
  };
  auto ln = [&](const float* i1, const float* i2, const float* i3,
                const float* g, const float* b, float* o, int mode, int pe) {
    ln_kernel<<<2048, 256, 0, stream>>>(i1, i2, i3, g, b, o, mode, pe);
  };

  auto mamba_layer = [&](float* x, int i) {
    gemm(x, 512, 0, m_in_w + (size_t)i * 2048 * 512, 512, 0, nullptr, nullptr,
         xz, 2048, 0, 2048, 2048, 512, 1.f, 0, 0, 1);
    conv_silu<<<8192, 256, 0, stream>>>(xz, m_cw + (size_t)i * 1024 * 4,
                                        m_cb + (size_t)i * 1024, u2);
    gemm(u2, 1024, 0, m_xp + (size_t)i * 64 * 1024, 1024, 0, nullptr, nullptr,
         xdbl, 64, 0, 2048, 64, 1024, 1.f, 0, 0, 1);
    gemm(xdbl, 64, 0, m_dtw + (size_t)i * 1024 * 32, 32, 0,
         m_dtb + (size_t)i * 1024, nullptr, dl, 1024, 0, 2048, 1024, 32, 1.f,
         1, 0, 1);
    scan_kernel<<<dim3(64, 8), 256, 0, stream>>>(dl, u2, xz, xdbl,
                                                 m_Alog + (size_t)i * 1024 * 16,
                                                 m_Dp + (size_t)i * 1024, ysb);
    gemm(ysb, 1024, 0, m_ow + (size_t)i * 512 * 1024, 1024, 0, nullptr, nullptr,
         mtmp, 512, 0, 2048, 512, 1024, 1.f, 0, 0, 1);
    ln(x, mtmp, nullptr, m_lng + (size_t)i * 512, m_lnb + (size_t)i * 512, x, 0, 0);
  };

  auto sub = [&](const float* s1, const float* s2, int i, float* o_str,
                 float* n1bf_, float* n2bf_) {
    ln(s1, nullptr, nullptr, sln_g + (size_t)i * 512, sln_b + (size_t)i * 512, n1bf_, 0, 0);
    ln(s2, nullptr, nullptr, sln_g + (size_t)i * 512, sln_b + (size_t)i * 512, n2bf_, 0, 0);
    const float* wq = qkv_w + ((size_t)i * 3 + 0) * 512 * 512;
    const float* wk = qkv_w + ((size_t)i * 3 + 1) * 512 * 512;
    const float* wv = qkv_w + ((size_t)i * 3 + 2) * 512 * 512;
    const float* bq = qkv_b + ((size_t)i * 3 + 0) * 512;
    const float* bk = qkv_b + ((size_t)i * 3 + 1) * 512;
    const float* bv = qkv_b + ((size_t)i * 3 + 2) * 512;
    // Q/K projections write head layout (B,H,S,hd) directly (omode 1)
    gemm(n1bf_, 512, 0, wq, 512, 0, bq, nullptr, qh, 0, 0, 2048, 512, 512, 1.f, 0, 1, 1);
    gemm(n2bf_, 512, 0, wk, 512, 0, bk, nullptr, kh, 0, 0, 2048, 512, 512, 1.f, 0, 1, 1);
    gemm(n2bf_, 512, 0, wv, 512, 0, bv, nullptr, vbf, 512, 0, 2048, 512, 512, 1.f, 0, 0, 1);
    to_heads_t<<<4096, 256, 0, stream>>>(vbf, vt);   // (B,H,hd,S)
    // scores[bh] = (1/8) * Qh @ Kh^T   (M=N=256, K=64, batch=64)
    gemm(qh, 64, 16384, kh, 64, 16384, nullptr, nullptr, scores, 256, 65536,
         256, 256, 64, 0.125f, 0, 0, 64);
    softmax_rows<<<16384, 256, 0, stream>>>(scores);
    // ob(flat b,s,d) = P @ V  via TN with W=Vt (N=64,K=256), omode 2
    gemm(scores, 256, 65536, vt, 256, 16384, nullptr, nullptr, ob, 512, 0,
         256, 64, 256, 1.f, 0, 2, 64);
    gemm(ob, 512, 0, aout_w + (size_t)i * 512 * 512, 512, 0,
         aout_b + (size_t)i * 512, s1, o_str, 512, 0, 2048, 512, 512, 1.f, 0, 0, 1);
  };

  auto ffn = [&](float* x, int i) {
    gemm(x, 512, 0, f_w1 + (size_t)i * 1024 * 512, 512, 0,
         f_b1 + (size_t)i * 1024, nullptr, hbuf, 1024, 0, 2048, 1024, 512, 1.f, 2, 0, 1);
    gemm(hbuf, 1024, 0, f_w2 + (size_t)i * 512 * 1024, 1024, 0,
         f_b2 + (size_t)i * 512, nullptr, h2, 512, 0, 2048, 512, 1024, 1.f, 0, 0, 1);
    ln(x, h2, nullptr, f_lng + (size_t)i * 512, f_lnb + (size_t)i * 512, x, 1, 0);
  };

  // ---- stems ----
  const float* ins[3] = {text, video, audio};
  for (int j = 0; j < 3; ++j) {
    gemm(ins[j], 512, 0, emb_w, 512, 0, emb_b, nullptr, sb[j], 512, 0,
         2048, 512, 512, 1.f, 0, 0, 1);
    ln(sb[j], nullptr, nullptr, ada_a, ada_b, sb[j], 1, 1);  // +PE, adaln
  }
  // ---- mamba 0..2 ----
  for (int j = 0; j < 3; ++j) mamba_layer(sb[j], j);
  // ---- self attention 0..2 ----
  sub(sb[0], sb[0], 0, sb[3], n1bf, n2bf);
  sub(sb[1], sb[1], 1, sb[4], n1bf, n2bf);
  sub(sb[2], sb[2], 2, sb[5], n1bf, n2bf);
  // ---- cross attention 3..5 (t=sb3, v=sb4, a=sb5) ----
  sub(sb[3], sb[5], 3, sb[0], n1bf, n2bf);
  sub(sb[4], sb[3], 4, sb[1], n1bf, n2bf);
  sub(sb[5], sb[4], 5, sb[2], n1bf, n2bf);
  // ---- mamba 3..5 ----
  for (int j = 0; j < 3; ++j) mamba_layer(sb[j], 3 + j);
  // ---- self attention 6..8 ----
  sub(sb[0], sb[0], 6, sb[3], n1bf, n2bf);
  sub(sb[1], sb[1], 7, sb[4], n1bf, n2bf);
  sub(sb[2], sb[2], 8, sb[5], n1bf, n2bf);
  // ---- ffn 0..2 ----
  for (int j = 0; j < 3; ++j) ffn(sb[3 + j], j);
  // ---- final norm: torch_ln(t+v+a) -> out ----
  ln(sb[3], sb[4], sb[5], n1_g, n1_b, outp, 0, 0);
}

// Round 5
// 2327.086 us; speedup vs baseline: 2.3359x; 1.1322x over previous
//
#include <hip/hip_runtime.h>
#include <hip/hip_bf16.h>
#include <math.h>

// ---------------- constants ----------------
// B=8 S=256 D=512 H=8 hd=64 DI=1024 DS=16 DC=4 DTR=32 DF=1024
// rows = B*S = 2048

using bf16x8 = __attribute__((ext_vector_type(8))) short;
using floatx16 = __attribute__((ext_vector_type(16))) float;

__device__ inline short2 f2bf2(float x, float y) {
  __hip_bfloat162 h = __float22bfloat162_rn(make_float2(x, y));
  return *reinterpret_cast<short2*>(&h);
}

// ---------------- reduction helpers (blockDim == 256) ----------------
__device__ inline float wave_sum(float v) {
#pragma unroll
  for (int o = 32; o > 0; o >>= 1) v += __shfl_xor(v, o, 64);
  return v;
}
__device__ inline float wave_maxf(float v) {
#pragma unroll
  for (int o = 32; o > 0; o >>= 1) v = fmaxf(v, __shfl_xor(v, o, 64));
  return v;
}
__device__ inline float block_sum(float v, float* sm) {
  v = wave_sum(v);
  if ((threadIdx.x & 63) == 0) sm[threadIdx.x >> 6] = v;
  __syncthreads();
  float r = sm[0] + sm[1] + sm[2] + sm[3];
  __syncthreads();
  return r;
}
__device__ inline float block_max(float v, float* sm) {
  v = wave_maxf(v);
  if ((threadIdx.x & 63) == 0) sm[threadIdx.x >> 6] = v;
  __syncthreads();
  float r = fmaxf(fmaxf(sm[0], sm[1]), fmaxf(sm[2], sm[3]));
  __syncthreads();
  return r;
}

// ---------------- bf16 MFMA GEMM  C = alpha*(A @ W^T) + bias, act, + res ----
// A: M x K f32 (row-major, lda). W: N x K f32 (row-major, ldw). f32 accumulate.
// grid (N/64, M/64, batch). 4 waves: quadrant mq=(wv&1)*32, nq=(wv>>1)*32.
// act: 0 none, 1 softplus, 2 relu.
// omode: 0 plain (idx=m*ldc+n, res usable)
//        1 heads: (b,s,h*64+c) -> (b,h,s,c)
//        2 unheads: batched bz=b*8+h; write flat (b,s,h*64+c)
//        3 qkv: sec=(n>>9)+osec; sec 0/1 -> head layout at sec*1048576;
//               sec 2 -> flat (m*512+d) at 2*1048576  (q,k,v regions)
// K-loop is software-pipelined: next slab's global loads issue after the
// LDS-write barrier, overlapping the MFMAs.
__global__ __launch_bounds__(256) void gemm_bf16(
    const float* __restrict__ A, int lda, long long sA,
    const float* __restrict__ W, int ldw, long long sW,
    const float* __restrict__ bias, const float* __restrict__ res,
    float* __restrict__ C, int ldc, long long sC,
    int K, float alpha, int act, int omode, int osec) {
  __shared__ short As[4 * 528];
  __shared__ short Bs[4 * 528];
  const int bz = blockIdx.z;
  A += sA * bz; W += sW * bz; C += sC * bz;
  const int m0 = blockIdx.y * 64, n0 = blockIdx.x * 64;
  const int tid = threadIdx.x, lane = tid & 63, wv = tid >> 6;
  const int mq = (wv & 1) * 32, nq = (wv >> 1) * 32;
  const int r31 = lane & 31, half = lane >> 5;
  const int mA = tid >> 2, kgA = tid & 3;   // staging: kg fast -> 128B segs
  floatx16 acc = {};
  const float* pa = A + (long long)(m0 + mA) * lda + kgA * 8;
  const float* pb = W + (long long)(n0 + mA) * ldw + kgA * 8;
  short* wa = As + kgA * 528 + mA * 8;
  short* wb = Bs + kgA * 528 + mA * 8;
  const short* ra = As + (mq + r31) * 8 + half * 528;
  const short* rb = Bs + (nq + r31) * 8 + half * 528;
  float4 a0 = *(const float4*)(pa);
  float4 a1 = *(const float4*)(pa + 4);
  float4 b0 = *(const float4*)(pb);
  float4 b1 = *(const float4*)(pb + 4);
  for (int k0 = 0; k0 < K; k0 += 32) {
    short ta[8], tb[8];
    *(short2*)&ta[0] = f2bf2(a0.x, a0.y); *(short2*)&ta[2] = f2bf2(a0.z, a0.w);
    *(short2*)&ta[4] = f2bf2(a1.x, a1.y); *(short2*)&ta[6] = f2bf2(a1.z, a1.w);
    *(short2*)&tb[0] = f2bf2(b0.x, b0.y); *(short2*)&tb[2] = f2bf2(b0.z, b0.w);
    *(short2*)&tb[4] = f2bf2(b1.x, b1.y); *(short2*)&tb[6] = f2bf2(b1.z, b1.w);
    __syncthreads();  // previous iter's frag reads done
    *(bf16x8*)wa = *(bf16x8*)ta;
    *(bf16x8*)wb = *(bf16x8*)tb;
    __syncthreads();
    if (k0 + 32 < K) {  // prefetch next slab, overlapped with MFMAs
      a0 = *(const float4*)(pa + k0 + 32);
      a1 = *(const float4*)(pa + k0 + 36);
      b0 = *(const float4*)(pb + k0 + 32);
      b1 = *(const float4*)(pb + k0 + 36);
    }
    // kg = half for k 0..15, kg = 2+half for k 16..31
    acc = __builtin_amdgcn_mfma_f32_32x32x16_bf16(
        *(const bf16x8*)ra, *(const bf16x8*)rb, acc, 0, 0, 0);
    acc = __builtin_amdgcn_mfma_f32_32x32x16_bf16(
        *(const bf16x8*)(ra + 2 * 528), *(const bf16x8*)(rb + 2 * 528), acc, 0, 0, 0);
  }
  const int n = n0 + nq + r31;
  const float bv = bias ? bias[n] : 0.f;
#pragma unroll
  for (int r = 0; r < 16; ++r) {
    const int m = m0 + mq + (r & 3) + 8 * (r >> 2) + 4 * half;
    float v = acc[r] * alpha + bv;
    if (act == 1) v = fmaxf(v, 0.f) + log1pf(expf(-fabsf(v)));
    else if (act == 2) v = fmaxf(v, 0.f);
    if (res) v += res[(long long)m * ldc + n];
    long long idx;
    if (omode == 0) idx = (long long)m * ldc + n;
    else if (omode == 1)
      idx = (long long)(m >> 8) * 131072 + (long long)(n >> 6) * 16384 +
            (m & 255) * 64 + (n & 63);
    else if (omode == 2)
      idx = (long long)(bz >> 3) * 131072 + (bz & 7) * 64 +
            (long long)m * 512 + n;
    else {
      const int sec = (n >> 9) + osec;
      const int d = n & 511;
      if (sec < 2)
        idx = (long long)sec * 1048576 +
              (((long long)(m >> 8) * 8 + (d >> 6)) * 256 + (m & 255)) * 64 +
              (d & 63);
      else
        idx = 2LL * 1048576 + (long long)m * 512 + d;
    }
    C[idx] = v;
  }
}

// ---------------- LayerNorm (one block per row of 512) ----------------
// mode 0: torch_ln  (biased var, eps=1e-5 inside sqrt)
// mode 1: custom_ln/adaln (unbiased std, eps=1e-6 added to s)
__device__ inline float pe_val(int bi, int c) {
  float f = expf((float)(c & ~1) * (-9.210340371976184f / 512.f)); // -ln(10000)/D
  float arg = (float)bi * f;
  return (c & 1) ? cosf(arg) : sinf(arg);
}
__global__ __launch_bounds__(256) void ln_kernel(
    const float* __restrict__ in1, const float* __restrict__ in2,
    const float* __restrict__ in3, const float* __restrict__ g,
    const float* __restrict__ bb, float* __restrict__ out, int mode, int add_pe) {
  __shared__ float sm[4];
  const int row = blockIdx.x, tid = threadIdx.x;
  const long long base = (long long)row * 512;
  float x0 = in1[base + tid];
  float x1 = in1[base + tid + 256];
  if (in2) { x0 += in2[base + tid]; x1 += in2[base + tid + 256]; }
  if (in3) { x0 += in3[base + tid]; x1 += in3[base + tid + 256]; }
  if (add_pe) {
    int bi = row >> 8;  // row / S
    x0 += pe_val(bi, tid);
    x1 += pe_val(bi, tid + 256);
  }
  float m = block_sum(x0 + x1, sm) * (1.f / 512.f);
  float d0 = x0 - m, d1 = x1 - m;
  float ss = block_sum(d0 * d0 + d1 * d1, sm);
  float r0, r1;
  if (mode == 0) {
    float rstd = rsqrtf(ss * (1.f / 512.f) + 1e-5f);
    r0 = d0 * rstd * g[tid] + bb[tid];
    r1 = d1 * rstd * g[tid + 256] + bb[tid + 256];
  } else {
    float s = sqrtf(ss * (1.f / 511.f));
    float inv = 1.f / (s + 1e-6f);
    r0 = g[tid] * d0 * inv + bb[tid];
    r1 = g[tid + 256] * d1 * inv + bb[tid + 256];
  }
  out[base + tid] = r0;
  out[base + tid + 256] = r1;
}

// ---------------- causal depthwise conv (DC=4) + SiLU ----------------
__global__ __launch_bounds__(256) void conv_silu(
    const float* __restrict__ xz, const float* __restrict__ cw,
    const float* __restrict__ cb, float* __restrict__ u2) {
  int idx = blockIdx.x * 256 + threadIdx.x;           // b*S*DI + t*DI + c
  int c = idx & 1023, t = (idx >> 10) & 255, b = idx >> 18;
  const float* base = xz + (long long)b * 256 * 2048;
  float acc = cb[c];
#pragma unroll
  for (int k = 0; k < 4; ++k) {
    int tt = t + k - 3;
    if (tt >= 0) acc += base[tt * 2048 + c] * cw[c * 4 + k];
  }
  u2[idx] = acc / (1.f + expf(-acc));
}

// ---------------- selective-scan, LDS-staged, double-buffered ----------------
// Block = (b, 16-d tile), 4 waves. While computing chunk c from LDS buf p,
// chunk c+1's global loads are in flight into registers (committed to buf 1-p
// after the compute barrier).
__global__ __launch_bounds__(256) void scan_kernel(
    const float* __restrict__ delta, const float* __restrict__ u2,
    const float* __restrict__ xz, const float* __restrict__ xdbl,
    const float* __restrict__ Alog, const float* __restrict__ Dp,
    float* __restrict__ ys) {
  __shared__ float sdel[2][64][16];
  __shared__ float su[2][64][16];
  __shared__ float sz[2][64][16];
  __shared__ float sxd[2][64][32];
  __shared__ float sy[64][16];
  const int tid = threadIdx.x;
  const int lane = tid & 63;
  const int wv = tid >> 6;                 // 0..3
  const int s = lane >> 2;                 // 0..15
  const int dsub = lane & 3;
  const int dl = wv * 4 + dsub;            // 0..15
  const int d0 = blockIdx.x * 16;
  const int d = d0 + dl;
  const int b = blockIdx.y;
  const float A = -expf(Alog[d * 16 + s]);
  const float Dd = Dp[d];
  const long long rowbase = (long long)b * 256;
  float rdel[4], ru[4], rz[4], rxd[8];
  auto issue = [&](int c) {
    const int t0 = c * 64;
#pragma unroll
    for (int k = 0; k < 4; ++k) {
      int e = k * 256 + tid;
      int t = e >> 4, dd = e & 15;
      long long r = rowbase + t0 + t;
      rdel[k] = delta[r * 1024 + d0 + dd];
      ru[k]   = u2[r * 1024 + d0 + dd];
      rz[k]   = xz[r * 2048 + 1024 + d0 + dd];
    }
#pragma unroll
    for (int k = 0; k < 8; ++k) {
      int e = k * 256 + tid;
      int t = e >> 5, j = e & 31;
      rxd[k] = xdbl[(rowbase + t0 + t) * 64 + 32 + j];
    }
  };
  auto commit = [&](int p) {
#pragma unroll
    for (int k = 0; k < 4; ++k) {
      int e = k * 256 + tid;
      int t = e >> 4, dd = e & 15;
      sdel[p][t][dd] = rdel[k]; su[p][t][dd] = ru[k]; sz[p][t][dd] = rz[k];
    }
#pragma unroll
    for (int k = 0; k < 8; ++k) {
      int e = k * 256 + tid;
      int t = e >> 5, j = e & 31;
      sxd[p][t][j] = rxd[k];
    }
  };
  issue(0);
  commit(0);
  float h = 0.f;
  for (int c = 0; c < 4; ++c) {
    __syncthreads();                 // buf (c&1) ready for all waves
    if (c < 3) issue(c + 1);         // loads overlap the serial compute
    const int p = c & 1;
#pragma unroll 4
    for (int t = 0; t < 64; ++t) {
      const float dt = sdel[p][t][dl];
      const float uu = su[p][t][dl];
      const float Bs = sxd[p][t][s];
      const float Cs = sxd[p][t][16 + s];
      h = __expf(dt * A) * h + dt * uu * Bs;
      float pp = h * Cs;
      pp += __shfl_xor(pp, 4, 64);
      pp += __shfl_xor(pp, 8, 64);
      pp += __shfl_xor(pp, 16, 64);
      pp += __shfl_xor(pp, 32, 64);
      if (s == 0) {
        const float zz = sz[p][t][dl];
        sy[t][dl] = (pp + Dd * uu) * (zz / (1.f + expf(-zz)));
      }
    }
    __syncthreads();                 // sy complete; buf 1-p reads done
    const int t0 = c * 64;
#pragma unroll
    for (int k = 0; k < 4; ++k) {
      int e = k * 256 + tid;
      int t = e >> 4, dd = e & 15;
      ys[(rowbase + t0 + t) * 1024 + d0 + dd] = sy[t][dd];
    }
    if (c < 3) commit((c + 1) & 1);
  }
}

// ---------------- softmax over rows of 256 (in place) ----------------
__global__ __launch_bounds__(256) void softmax_rows(float* __restrict__ S) {
  __shared__ float sm[4];
  float* p = S + (long long)blockIdx.x * 256;
  float v = p[threadIdx.x];
  float m = block_max(v, sm);
  float e = expf(v - m);
  float s = block_sum(e, sm);
  p[threadIdx.x] = e / s;
}

// ---------------- V transpose: (B,S,H*hd) -> (B,H,hd,S) ----------------
__global__ __launch_bounds__(256) void to_heads_t(const float* __restrict__ in,
                                                  float* __restrict__ out) {
  int idx = blockIdx.x * 256 + threadIdx.x;
  int s = idx & 255, c = (idx >> 8) & 63, h = (idx >> 14) & 7, b = idx >> 17;
  out[idx] = in[((b * 256 + s) * 512) + h * 64 + c];
}

// ---------------- host orchestration ----------------
extern "C" void kernel_launch(void* const* d_in, const int* in_sizes, int n_in,
                              void* d_out, int out_size, void* d_ws, size_t ws_size,
                              hipStream_t stream) {
  (void)in_sizes; (void)n_in; (void)out_size; (void)ws_size;
  const float* text   = (const float*)d_in[0];
  const float* video  = (const float*)d_in[1];
  const float* audio  = (const float*)d_in[2];
  const float* emb_w  = (const float*)d_in[3];
  const float* emb_b  = (const float*)d_in[4];
  const float* ada_a  = (const float*)d_in[5];
  const float* ada_b  = (const float*)d_in[6];
  const float* m_in_w = (const float*)d_in[7];
  const float* m_cw   = (const float*)d_in[8];
  const float* m_cb   = (const float*)d_in[9];
  const float* m_xp   = (const float*)d_in[10];
  const float* m_dtw  = (const float*)d_in[11];
  const float* m_dtb  = (const float*)d_in[12];
  const float* m_Alog = (const float*)d_in[13];
  const float* m_Dp   = (const float*)d_in[14];
  const float* m_ow   = (const float*)d_in[15];
  const float* m_lng  = (const float*)d_in[16];
  const float* m_lnb  = (const float*)d_in[17];
  const float* qkv_w  = (const float*)d_in[18];
  const float* qkv_b  = (const float*)d_in[19];
  const float* aout_w = (const float*)d_in[20];
  const float* aout_b = (const float*)d_in[21];
  const float* sln_g  = (const float*)d_in[22];
  const float* sln_b  = (const float*)d_in[23];
  const float* f_w1   = (const float*)d_in[24];
  const float* f_b1   = (const float*)d_in[25];
  const float* f_w2   = (const float*)d_in[26];
  const float* f_b2   = (const float*)d_in[27];
  const float* f_lng  = (const float*)d_in[28];
  const float* f_lnb  = (const float*)d_in[29];
  const float* n1_g   = (const float*)d_in[30];
  const float* n1_b   = (const float*)d_in[31];
  float* outp = (float*)d_out;

  // workspace layout (floats)
  float* ws = (float*)d_ws;
  size_t off = 0;
  auto alloc = [&](size_t n) { float* p = ws + off; off += n; return p; };
  float* sb[6];
  for (int i = 0; i < 6; ++i) sb[i] = alloc(2048 * 512);
  float* xz   = alloc(2048 * 2048);   // also: attention scores (B*H*S*S)
  float* u2   = alloc(2048 * 1024);   // also: qkv region [qh | kh ...]
  float* dl   = alloc(2048 * 1024);   // also: [... kh end | vbf]
  float* ysb  = alloc(2048 * 1024);   // also: vt
  float* xdbl = alloc(2048 * 64);
  float* n1bf = alloc(2048 * 512);    // also: mtmp, ffn h2
  float* n2bf = alloc(2048 * 512);    // also: ob (PV output, flat)
  float* vbf  = alloc(2048 * 512);    // (unused slack)
  (void)vbf;
  float* scores = xz;
  float* qkv = u2;                    // qh = qkv, kh = qkv+1M, vflat = qkv+2M
  float* qh = qkv;
  float* kh = qkv + 1048576;
  float* vflat = qkv + 2097152;
  float* vt = ysb;
  float* ob = n2bf; float* mtmp = n1bf;
  float* hbuf = u2; float* h2 = n1bf;

  auto gemm = [&](const float* A, int lda, long long sA2,
                  const float* W, int ldw, long long sW2,
                  const float* bias, const float* res, float* C, int ldc,
                  long long sC2, int M, int N, int K, float alpha, int act,
                  int omode, int osec, int batch) {
    dim3 g(N / 64, M / 64, batch);
    gemm_bf16<<<g, 256, 0, stream>>>(A, lda, sA2, W, ldw, sW2, bias, res, C,
                                     ldc, sC2, K, alpha, act, omode, osec);
  };
  auto ln = [&](const float* i1, const float* i2, const float* i3,
                const float* g, const float* b, float* o, int mode, int pe) {
    ln_kernel<<<2048, 256, 0, stream>>>(i1, i2, i3, g, b, o, mode, pe);
  };

  auto mamba_layer = [&](float* x, int i) {
    gemm(x, 512, 0, m_in_w + (size_t)i * 2048 * 512, 512, 0, nullptr, nullptr,
         xz, 2048, 0, 2048, 2048, 512, 1.f, 0, 0, 0, 1);
    conv_silu<<<8192, 256, 0, stream>>>(xz, m_cw + (size_t)i * 1024 * 4,
                                        m_cb + (size_t)i * 1024, u2);
    gemm(u2, 1024, 0, m_xp + (size_t)i * 64 * 1024, 1024, 0, nullptr, nullptr,
         xdbl, 64, 0, 2048, 64, 1024, 1.f, 0, 0, 0, 1);
    gemm(xdbl, 64, 0, m_dtw + (size_t)i * 1024 * 32, 32, 0,
         m_dtb + (size_t)i * 1024, nullptr, dl, 1024, 0, 2048, 1024, 32, 1.f,
         1, 0, 0, 1);
    scan_kernel<<<dim3(64, 8), 256, 0, stream>>>(dl, u2, xz, xdbl,
                                                 m_Alog + (size_t)i * 1024 * 16,
                                                 m_Dp + (size_t)i * 1024, ysb);
    gemm(ysb, 1024, 0, m_ow + (size_t)i * 512 * 1024, 1024, 0, nullptr, nullptr,
         mtmp, 512, 0, 2048, 512, 1024, 1.f, 0, 0, 0, 1);
    ln(x, mtmp, nullptr, m_lng + (size_t)i * 512, m_lnb + (size_t)i * 512, x, 0, 0);
  };

  auto sub = [&](const float* s1, const float* s2, int i, float* o_str) {
    const float* wq = qkv_w + ((size_t)i * 3 + 0) * 512 * 512;
    const float* wk = qkv_w + ((size_t)i * 3 + 1) * 512 * 512;
    const float* bq = qkv_b + ((size_t)i * 3 + 0) * 512;
    const float* bk = qkv_b + ((size_t)i * 3 + 1) * 512;
    ln(s1, nullptr, nullptr, sln_g + (size_t)i * 512, sln_b + (size_t)i * 512, n1bf, 0, 0);
    if (s1 == s2) {
      // fused QKV: N=1536 (wq,wk,wv contiguous), q/k -> head layout, v -> flat
      gemm(n1bf, 512, 0, wq, 512, 0, bq, nullptr, qkv, 0, 0,
           2048, 1536, 512, 1.f, 0, 3, 0, 1);
    } else {
      ln(s2, nullptr, nullptr, sln_g + (size_t)i * 512, sln_b + (size_t)i * 512, n2bf, 0, 0);
      gemm(n1bf, 512, 0, wq, 512, 0, bq, nullptr, qh, 0, 0,
           2048, 512, 512, 1.f, 0, 1, 0, 1);
      // fused KV from n2bf: osec=1 -> k to sec1 (head), v to sec2 (flat)
      gemm(n2bf, 512, 0, wk, 512, 0, bk, nullptr, qkv, 0, 0,
           2048, 1024, 512, 1.f, 0, 3, 1, 1);
    }
    to_heads_t<<<4096, 256, 0, stream>>>(vflat, vt);   // (B,H,hd,S)
    // scores[bh] = (1/8) * Qh @ Kh^T   (M=N=256, K=64, batch=64)
    gemm(qh, 64, 16384, kh, 64, 16384, nullptr, nullptr, scores, 256, 65536,
         256, 256, 64, 0.125f, 0, 0, 0, 64);
    softmax_rows<<<16384, 256, 0, stream>>>(scores);
    // ob(flat b,s,d) = P @ V  via TN with W=Vt (N=64,K=256), omode 2
    gemm(scores, 256, 65536, vt, 256, 16384, nullptr, nullptr, ob, 512, 0,
         256, 64, 256, 1.f, 0, 2, 0, 64);
    gemm(ob, 512, 0, aout_w + (size_t)i * 512 * 512, 512, 0,
         aout_b + (size_t)i * 512, s1, o_str, 512, 0, 2048, 512, 512, 1.f, 0,
         0, 0, 1);
  };

  auto ffn = [&](float* x, int i) {
    gemm(x, 512, 0, f_w1 + (size_t)i * 1024 * 512, 512, 0,
         f_b1 + (size_t)i * 1024, nullptr, hbuf, 1024, 0, 2048, 1024, 512, 1.f,
         2, 0, 0, 1);
    gemm(hbuf, 1024, 0, f_w2 + (size_t)i * 512 * 1024, 1024, 0,
         f_b2 + (size_t)i * 512, nullptr, h2, 512, 0, 2048, 512, 1024, 1.f, 0,
         0, 0, 1);
    ln(x, h2, nullptr, f_lng + (size_t)i * 512, f_lnb + (size_t)i * 512, x, 1, 0);
  };

  // ---- stems ----
  const float* ins[3] = {text, video, audio};
  for (int j = 0; j < 3; ++j) {
    gemm(ins[j], 512, 0, emb_w, 512, 0, emb_b, nullptr, sb[j], 512, 0,
         2048, 512, 512, 1.f, 0, 0, 0, 1);
    ln(sb[j], nullptr, nullptr, ada_a, ada_b, sb[j], 1, 1);  // +PE, adaln
  }
  // ---- mamba 0..2 ----
  for (int j = 0; j < 3; ++j) mamba_layer(sb[j], j);
  // ---- self attention 0..2 ----
  sub(sb[0], sb[0], 0, sb[3]);
  sub(sb[1], sb[1], 1, sb[4]);
  sub(sb[2], sb[2], 2, sb[5]);
  // ---- cross attention 3..5 (t=sb3, v=sb4, a=sb5) ----
  sub(sb[3], sb[5], 3, sb[0]);
  sub(sb[4], sb[3], 4, sb[1]);
  sub(sb[5], sb[4], 5, sb[2]);
  // ---- mamba 3..5 ----
  for (int j = 0; j < 3; ++j) mamba_layer(sb[j], 3 + j);
  // ---- self attention 6..8 ----
  sub(sb[0], sb[0], 6, sb[3]);
  sub(sb[1], sb[1], 7, sb[4]);
  sub(sb[2], sb[2], 8, sb[5]);
  // ---- ffn 0..2 ----
  for (int j = 0; j < 3; ++j) ffn(sb[3 + j], j);
  // ---- final norm: torch_ln(t+v+a) -> out ----
  ln(sb[3], sb[4], sb[5], n1_g, n1_b, outp, 0, 0);
}

// Round 6
// 1904.295 us; speedup vs baseline: 2.8545x; 1.2220x over previous
//
#include <hip/hip_runtime.h>
#include <hip/hip_bf16.h>
#include <math.h>

// ---------------- constants ----------------
// B=8 S=256 D=512 H=8 hd=64 DI=1024 DS=16 DC=4 DTR=32 DF=1024
// rows = B*S = 2048

using bf16x8 = __attribute__((ext_vector_type(8))) short;
using floatx16 = __attribute__((ext_vector_type(16))) float;

__device__ inline short f2bf(float x) {
  __hip_bfloat16 h = __float2bfloat16(x);
  return *reinterpret_cast<short*>(&h);
}

// ---------------- reduction helpers (blockDim == 256) ----------------
__device__ inline float wave_sum(float v) {
#pragma unroll
  for (int o = 32; o > 0; o >>= 1) v += __shfl_xor(v, o, 64);
  return v;
}
__device__ inline float wave_maxf(float v) {
#pragma unroll
  for (int o = 32; o > 0; o >>= 1) v = fmaxf(v, __shfl_xor(v, o, 64));
  return v;
}
__device__ inline float block_sum(float v, float* sm) {
  v = wave_sum(v);
  if ((threadIdx.x & 63) == 0) sm[threadIdx.x >> 6] = v;
  __syncthreads();
  float r = sm[0] + sm[1] + sm[2] + sm[3];
  __syncthreads();
  return r;
}
__device__ inline float block_max(float v, float* sm) {
  v = wave_maxf(v);
  if ((threadIdx.x & 63) == 0) sm[threadIdx.x >> 6] = v;
  __syncthreads();
  float r = fmaxf(fmaxf(sm[0], sm[1]), fmaxf(sm[2], sm[3]));
  __syncthreads();
  return r;
}

// ---------------- f32 -> bf16 elementwise (n multiple of 1024) ----------------
__global__ __launch_bounds__(256) void cvt_bf16(const float* __restrict__ in,
                                                short* __restrict__ out) {
  int i = (blockIdx.x * 256 + threadIdx.x) * 4;
  float4 v = *(const float4*)(in + i);
  short4 o;
  o.x = f2bf(v.x); o.y = f2bf(v.y); o.z = f2bf(v.z); o.w = f2bf(v.w);
  *(short4*)(out + i) = o;
}

// ---------------- bf16 MFMA GEMM  C = alpha*(A @ W^T) + bias, act, + res ----
// A: M x K bf16 (row-major, lda). W: N x K bf16 (row-major, ldw). f32 acc.
// grid (N/64, M/64, batch). 4 waves: quadrant mq=(wv&1)*32, nq=(wv>>1)*32.
// act: 0 none, 1 softplus, 2 relu.
// omode: 0 plain (idx=m*ldc+n, res usable)
//        1 heads: (b,s,h*64+c) -> (b,h,s,c)
//        2 unheads: batched bz=b*8+h; write flat (b,s,h*64+c)
//        3 qkv: sec=(n>>9)+osec; sec 0/1 -> head layout at sec*1048576;
//               sec 2 -> flat (m*512+d) at 2*1048576  (q,k,v regions)
// C (f32) and/or Cbf (bf16) written if non-null.
// No in-loop cvt: operands pre-converted; 16 B/lane loads; pipelined.
__global__ __launch_bounds__(256) void gemm_bf16(
    const short* __restrict__ A, int lda, long long sA,
    const short* __restrict__ W, int ldw, long long sW,
    const float* __restrict__ bias, const float* __restrict__ res,
    float* __restrict__ C, short* __restrict__ Cbf, int ldc, long long sC,
    int K, float alpha, int act, int omode, int osec) {
  __shared__ short As[4 * 528];
  __shared__ short Bs[4 * 528];
  const int bz = blockIdx.z;
  A += sA * bz; W += sW * bz;
  if (C) C += sC * bz;
  if (Cbf) Cbf += sC * bz;
  const int m0 = blockIdx.y * 64, n0 = blockIdx.x * 64;
  const int tid = threadIdx.x, lane = tid & 63, wv = tid >> 6;
  const int mq = (wv & 1) * 32, nq = (wv >> 1) * 32;
  const int r31 = lane & 31, half = lane >> 5;
  const int mA = tid >> 2, kgA = tid & 3;   // staging: kg fast
  floatx16 acc = {};
  const short* pa = A + (long long)(m0 + mA) * lda + kgA * 8;
  const short* pb = W + (long long)(n0 + mA) * ldw + kgA * 8;
  short* wa = As + kgA * 528 + mA * 8;
  short* wb = Bs + kgA * 528 + mA * 8;
  const short* ra = As + (mq + r31) * 8 + half * 528;
  const short* rb = Bs + (nq + r31) * 8 + half * 528;
  bf16x8 av = *(const bf16x8*)pa;
  bf16x8 bv = *(const bf16x8*)pb;
  for (int k0 = 0; k0 < K; k0 += 32) {
    __syncthreads();  // previous iter's frag reads done
    *(bf16x8*)wa = av;
    *(bf16x8*)wb = bv;
    __syncthreads();
    if (k0 + 32 < K) {  // prefetch next slab, overlapped with MFMAs
      av = *(const bf16x8*)(pa + k0 + 32);
      bv = *(const bf16x8*)(pb + k0 + 32);
    }
    acc = __builtin_amdgcn_mfma_f32_32x32x16_bf16(
        *(const bf16x8*)ra, *(const bf16x8*)rb, acc, 0, 0, 0);
    acc = __builtin_amdgcn_mfma_f32_32x32x16_bf16(
        *(const bf16x8*)(ra + 2 * 528), *(const bf16x8*)(rb + 2 * 528), acc, 0, 0, 0);
  }
  const int n = n0 + nq + r31;
  const float bvb = bias ? bias[n] : 0.f;
#pragma unroll
  for (int r = 0; r < 16; ++r) {
    const int m = m0 + mq + (r & 3) + 8 * (r >> 2) + 4 * half;
    float v = acc[r] * alpha + bvb;
    if (act == 1) v = fmaxf(v, 0.f) + log1pf(expf(-fabsf(v)));
    else if (act == 2) v = fmaxf(v, 0.f);
    if (res) v += res[(long long)m * ldc + n];
    long long idx;
    if (omode == 0) idx = (long long)m * ldc + n;
    else if (omode == 1)
      idx = (long long)(m >> 8) * 131072 + (long long)(n >> 6) * 16384 +
            (m & 255) * 64 + (n & 63);
    else if (omode == 2)
      idx = (long long)(bz >> 3) * 131072 + (bz & 7) * 64 +
            (long long)m * 512 + n;
    else {
      const int sec = (n >> 9) + osec;
      const int d = n & 511;
      if (sec < 2)
        idx = (long long)sec * 1048576 +
              (((long long)(m >> 8) * 8 + (d >> 6)) * 256 + (m & 255)) * 64 +
              (d & 63);
      else
        idx = 2LL * 1048576 + (long long)m * 512 + d;
    }
    if (C) C[idx] = v;
    if (Cbf) Cbf[idx] = f2bf(v);
  }
}

// ---------------- LayerNorm (one block per row of 512) ----------------
// mode 0: torch_ln  (biased var, eps=1e-5 inside sqrt)
// mode 1: custom_ln/adaln (unbiased std, eps=1e-6 added to s)
// out (f32) and/or obf (bf16) written if non-null.
__device__ inline float pe_val(int bi, int c) {
  float f = expf((float)(c & ~1) * (-9.210340371976184f / 512.f)); // -ln(10000)/D
  float arg = (float)bi * f;
  return (c & 1) ? cosf(arg) : sinf(arg);
}
__global__ __launch_bounds__(256) void ln_kernel(
    const float* __restrict__ in1, const float* __restrict__ in2,
    const float* __restrict__ in3, const float* __restrict__ g,
    const float* __restrict__ bb, float* __restrict__ out,
    short* __restrict__ obf, int mode, int add_pe) {
  __shared__ float sm[4];
  const int row = blockIdx.x, tid = threadIdx.x;
  const long long base = (long long)row * 512;
  float x0 = in1[base + tid];
  float x1 = in1[base + tid + 256];
  if (in2) { x0 += in2[base + tid]; x1 += in2[base + tid + 256]; }
  if (in3) { x0 += in3[base + tid]; x1 += in3[base + tid + 256]; }
  if (add_pe) {
    int bi = row >> 8;  // row / S
    x0 += pe_val(bi, tid);
    x1 += pe_val(bi, tid + 256);
  }
  float m = block_sum(x0 + x1, sm) * (1.f / 512.f);
  float d0 = x0 - m, d1 = x1 - m;
  float ss = block_sum(d0 * d0 + d1 * d1, sm);
  float r0, r1;
  if (mode == 0) {
    float rstd = rsqrtf(ss * (1.f / 512.f) + 1e-5f);
    r0 = d0 * rstd * g[tid] + bb[tid];
    r1 = d1 * rstd * g[tid + 256] + bb[tid + 256];
  } else {
    float s = sqrtf(ss * (1.f / 511.f));
    float inv = 1.f / (s + 1e-6f);
    r0 = g[tid] * d0 * inv + bb[tid];
    r1 = g[tid + 256] * d1 * inv + bb[tid + 256];
  }
  if (out) { out[base + tid] = r0; out[base + tid + 256] = r1; }
  if (obf) { obf[base + tid] = f2bf(r0); obf[base + tid + 256] = f2bf(r1); }
}

// ---------------- causal depthwise conv (DC=4) + SiLU ----------------
__global__ __launch_bounds__(256) void conv_silu(
    const float* __restrict__ xz, const float* __restrict__ cw,
    const float* __restrict__ cb, float* __restrict__ u2,
    short* __restrict__ u2bf) {
  int idx = blockIdx.x * 256 + threadIdx.x;           // b*S*DI + t*DI + c
  int c = idx & 1023, t = (idx >> 10) & 255, b = idx >> 18;
  const float* base = xz + (long long)b * 256 * 2048;
  float acc = cb[c];
#pragma unroll
  for (int k = 0; k < 4; ++k) {
    int tt = t + k - 3;
    if (tt >= 0) acc += base[tt * 2048 + c] * cw[c * 4 + k];
  }
  float v = acc / (1.f + expf(-acc));
  u2[idx] = v;
  u2bf[idx] = f2bf(v);
}

// ---------------- selective-scan, LDS-staged, double-buffered ----------------
// Output ys written bf16 (feeds only the out-proj GEMM).
__global__ __launch_bounds__(256) void scan_kernel(
    const float* __restrict__ delta, const float* __restrict__ u2,
    const float* __restrict__ xz, const float* __restrict__ xdbl,
    const float* __restrict__ Alog, const float* __restrict__ Dp,
    short* __restrict__ ys) {
  __shared__ float sdel[2][64][16];
  __shared__ float su[2][64][16];
  __shared__ float sz[2][64][16];
  __shared__ float sxd[2][64][32];
  __shared__ float sy[64][16];
  const int tid = threadIdx.x;
  const int lane = tid & 63;
  const int wv = tid >> 6;                 // 0..3
  const int s = lane >> 2;                 // 0..15
  const int dsub = lane & 3;
  const int dl = wv * 4 + dsub;            // 0..15
  const int d0 = blockIdx.x * 16;
  const int d = d0 + dl;
  const int b = blockIdx.y;
  const float A = -expf(Alog[d * 16 + s]);
  const float Dd = Dp[d];
  const long long rowbase = (long long)b * 256;
  float rdel[4], ru[4], rz[4], rxd[8];
  auto issue = [&](int c) {
    const int t0 = c * 64;
#pragma unroll
    for (int k = 0; k < 4; ++k) {
      int e = k * 256 + tid;
      int t = e >> 4, dd = e & 15;
      long long r = rowbase + t0 + t;
      rdel[k] = delta[r * 1024 + d0 + dd];
      ru[k]   = u2[r * 1024 + d0 + dd];
      rz[k]   = xz[r * 2048 + 1024 + d0 + dd];
    }
#pragma unroll
    for (int k = 0; k < 8; ++k) {
      int e = k * 256 + tid;
      int t = e >> 5, j = e & 31;
      rxd[k] = xdbl[(rowbase + t0 + t) * 64 + 32 + j];
    }
  };
  auto commit = [&](int p) {
#pragma unroll
    for (int k = 0; k < 4; ++k) {
      int e = k * 256 + tid;
      int t = e >> 4, dd = e & 15;
      sdel[p][t][dd] = rdel[k]; su[p][t][dd] = ru[k]; sz[p][t][dd] = rz[k];
    }
#pragma unroll
    for (int k = 0; k < 8; ++k) {
      int e = k * 256 + tid;
      int t = e >> 5, j = e & 31;
      sxd[p][t][j] = rxd[k];
    }
  };
  issue(0);
  commit(0);
  float h = 0.f;
  for (int c = 0; c < 4; ++c) {
    __syncthreads();                 // buf (c&1) ready for all waves
    if (c < 3) issue(c + 1);         // loads overlap the serial compute
    const int p = c & 1;
#pragma unroll 4
    for (int t = 0; t < 64; ++t) {
      const float dt = sdel[p][t][dl];
      const float uu = su[p][t][dl];
      const float Bs = sxd[p][t][s];
      const float Cs = sxd[p][t][16 + s];
      h = __expf(dt * A) * h + dt * uu * Bs;
      float pp = h * Cs;
      pp += __shfl_xor(pp, 4, 64);
      pp += __shfl_xor(pp, 8, 64);
      pp += __shfl_xor(pp, 16, 64);
      pp += __shfl_xor(pp, 32, 64);
      if (s == 0) {
        const float zz = sz[p][t][dl];
        sy[t][dl] = (pp + Dd * uu) * (zz / (1.f + expf(-zz)));
      }
    }
    __syncthreads();                 // sy complete; buf 1-p reads done
    const int t0 = c * 64;
#pragma unroll
    for (int k = 0; k < 4; ++k) {
      int e = k * 256 + tid;
      int t = e >> 4, dd = e & 15;
      ys[(rowbase + t0 + t) * 1024 + d0 + dd] = f2bf(sy[t][dd]);
    }
    if (c < 3) commit((c + 1) & 1);
  }
}

// ---------------- softmax rows of 256: f32 in -> bf16 out ----------------
__global__ __launch_bounds__(256) void softmax_rows(const float* __restrict__ S,
                                                    short* __restrict__ Sbf) {
  __shared__ float sm[4];
  const float* p = S + (long long)blockIdx.x * 256;
  float v = p[threadIdx.x];
  float m = block_max(v, sm);
  float e = expf(v - m);
  float s = block_sum(e, sm);
  Sbf[(long long)blockIdx.x * 256 + threadIdx.x] = f2bf(e / s);
}

// ---------------- V transpose (bf16): (B,S,H*hd) -> (B,H,hd,S) ----------------
__global__ __launch_bounds__(256) void to_heads_t(const short* __restrict__ in,
                                                  short* __restrict__ out) {
  int idx = blockIdx.x * 256 + threadIdx.x;
  int s = idx & 255, c = (idx >> 8) & 63, h = (idx >> 14) & 7, b = idx >> 17;
  out[idx] = in[((b * 256 + s) * 512) + h * 64 + c];
}

// ---------------- host orchestration ----------------
extern "C" void kernel_launch(void* const* d_in, const int* in_sizes, int n_in,
                              void* d_out, int out_size, void* d_ws, size_t ws_size,
                              hipStream_t stream) {
  (void)in_sizes; (void)n_in; (void)out_size; (void)ws_size;
  const float* text   = (const float*)d_in[0];
  const float* video  = (const float*)d_in[1];
  const float* audio  = (const float*)d_in[2];
  const float* emb_w  = (const float*)d_in[3];
  const float* emb_b  = (const float*)d_in[4];
  const float* ada_a  = (const float*)d_in[5];
  const float* ada_b  = (const float*)d_in[6];
  const float* m_in_w = (const float*)d_in[7];
  const float* m_cw   = (const float*)d_in[8];
  const float* m_cb   = (const float*)d_in[9];
  const float* m_xp   = (const float*)d_in[10];
  const float* m_dtw  = (const float*)d_in[11];
  const float* m_dtb  = (const float*)d_in[12];
  const float* m_Alog = (const float*)d_in[13];
  const float* m_Dp   = (const float*)d_in[14];
  const float* m_ow   = (const float*)d_in[15];
  const float* m_lng  = (const float*)d_in[16];
  const float* m_lnb  = (const float*)d_in[17];
  const float* qkv_w  = (const float*)d_in[18];
  const float* qkv_b  = (const float*)d_in[19];
  const float* aout_w = (const float*)d_in[20];
  const float* aout_b = (const float*)d_in[21];
  const float* sln_g  = (const float*)d_in[22];
  const float* sln_b  = (const float*)d_in[23];
  const float* f_w1   = (const float*)d_in[24];
  const float* f_b1   = (const float*)d_in[25];
  const float* f_w2   = (const float*)d_in[26];
  const float* f_b2   = (const float*)d_in[27];
  const float* f_lng  = (const float*)d_in[28];
  const float* f_lnb  = (const float*)d_in[29];
  const float* n1_g   = (const float*)d_in[30];
  const float* n1_b   = (const float*)d_in[31];
  float* outp = (float*)d_out;

  // ---------- workspace layout (units = floats; bf16 arenas cast) ----------
  float* ws = (float*)d_ws;
  size_t off = 0;
  auto alloc = [&](size_t n) { float* p = ws + off; off += n; return p; };
  auto allocs = [&](size_t n_bf16) { return (short*)alloc((n_bf16 + 1) / 2); };
  float* sb[6];
  for (int i = 0; i < 6; ++i) sb[i] = alloc(2048 * 512);
  short* sbbf[6];
  for (int i = 0; i < 6; ++i) sbbf[i] = allocs(2048 * 512);
  float* big0 = alloc(2048 * 2048);        // xz f32 | scores f32
  float* big1 = alloc(2048 * 1024);        // u2 f32 | scores_bf (bf16)
  float* big2 = alloc(2048 * 1024);        // dl f32 | qkvbf (bf16, 3M elems)
  float* big3 = alloc(1048576);            // ysbf | vt+ob | inbf (bf16)
  float* big4 = alloc(2048 * 512);         // mtmp f32 | h2 f32
  short* big5 = allocs(2048 * 1024);       // u2bf | hbufbf
  float* xdbl   = alloc(2048 * 64);
  short* xdblbf = allocs(2048 * 64);
  short* n1bf   = allocs(2048 * 512);
  short* n2bf   = allocs(2048 * 512);
  // bf16 weight arena
  short* embbf   = allocs(512 * 512);
  short* minbf   = allocs(6 * 2048 * 512);
  short* mxpbf   = allocs(6 * 64 * 1024);
  short* mdtwbf  = allocs(6 * 1024 * 32);
  short* mowbf   = allocs(6 * 512 * 1024);
  short* qkvwbf  = allocs(9 * 3 * 512 * 512);
  short* aoutwbf = allocs(9 * 512 * 512);
  short* fw1bf   = allocs(3 * 1024 * 512);
  short* fw2bf   = allocs(3 * 512 * 1024);

  float* xz = big0;      float* scoresF = big0;
  float* u2 = big1;      short* scoresBf = (short*)big1;
  float* dlb = big2;     short* qkvbf = (short*)big2;
  short* ysbf = (short*)big3;
  short* vtbf = (short*)big3;  short* obbf = (short*)big3 + 1048576;
  short* inbf = (short*)big3;
  float* mtmp = big4;    float* h2 = big4;
  short* u2bf = big5;    short* hbufbf = big5;
  short* qhbf = qkvbf;
  short* khbf = qkvbf + 1048576;
  short* vflatbf = qkvbf + 2097152;

  auto cvt = [&](const float* in, short* out, int n) {
    cvt_bf16<<<n / 1024, 256, 0, stream>>>(in, out);
  };
  auto gemm = [&](const short* A, int lda, long long sA2,
                  const short* W, int ldw, long long sW2,
                  const float* bias, const float* res,
                  float* C, short* Cbf, int ldc, long long sC2,
                  int M, int N, int K, float alpha, int act,
                  int omode, int osec, int batch) {
    dim3 g(N / 64, M / 64, batch);
    gemm_bf16<<<g, 256, 0, stream>>>(A, lda, sA2, W, ldw, sW2, bias, res, C,
                                     Cbf, ldc, sC2, K, alpha, act, omode, osec);
  };
  auto ln = [&](const float* i1, const float* i2, const float* i3,
                const float* g, const float* b, float* o, short* obf,
                int mode, int pe) {
    ln_kernel<<<2048, 256, 0, stream>>>(i1, i2, i3, g, b, o, obf, mode, pe);
  };

  // ---- pre-convert all weights to bf16 (once per call) ----
  cvt(emb_w,  embbf,   512 * 512);
  cvt(m_in_w, minbf,   6 * 2048 * 512);
  cvt(m_xp,   mxpbf,   6 * 64 * 1024);
  cvt(m_dtw,  mdtwbf,  6 * 1024 * 32);
  cvt(m_ow,   mowbf,   6 * 512 * 1024);
  cvt(qkv_w,  qkvwbf,  9 * 3 * 512 * 512);
  cvt(aout_w, aoutwbf, 9 * 512 * 512);
  cvt(f_w1,   fw1bf,   3 * 1024 * 512);
  cvt(f_w2,   fw2bf,   3 * 512 * 1024);

  auto mamba_layer = [&](float* x, short* xbf, int i) {
    gemm(xbf, 512, 0, minbf + (size_t)i * 1048576, 512, 0, nullptr, nullptr,
         xz, nullptr, 2048, 0, 2048, 2048, 512, 1.f, 0, 0, 0, 1);
    conv_silu<<<8192, 256, 0, stream>>>(xz, m_cw + (size_t)i * 4096,
                                        m_cb + (size_t)i * 1024, u2, u2bf);
    gemm(u2bf, 1024, 0, mxpbf + (size_t)i * 65536, 1024, 0, nullptr, nullptr,
         xdbl, xdblbf, 64, 0, 2048, 64, 1024, 1.f, 0, 0, 0, 1);
    gemm(xdblbf, 64, 0, mdtwbf + (size_t)i * 32768, 32, 0,
         m_dtb + (size_t)i * 1024, nullptr, dlb, nullptr, 1024, 0,
         2048, 1024, 32, 1.f, 1, 0, 0, 1);
    scan_kernel<<<dim3(64, 8), 256, 0, stream>>>(dlb, u2, xz, xdbl,
                                                 m_Alog + (size_t)i * 16384,
                                                 m_Dp + (size_t)i * 1024, ysbf);
    gemm(ysbf, 1024, 0, mowbf + (size_t)i * 524288, 1024, 0, nullptr, nullptr,
         mtmp, nullptr, 512, 0, 2048, 512, 1024, 1.f, 0, 0, 0, 1);
    ln(x, mtmp, nullptr, m_lng + (size_t)i * 512, m_lnb + (size_t)i * 512,
       x, xbf, 0, 0);
  };

  auto sub = [&](const float* s1, const float* s2, int i, float* o_str,
                 short* o_strbf) {
    const short* wfull = qkvwbf + (size_t)i * 786432;
    const float* bfull = qkv_b + (size_t)i * 1536;
    ln(s1, nullptr, nullptr, sln_g + (size_t)i * 512, sln_b + (size_t)i * 512,
       nullptr, n1bf, 0, 0);
    if (s1 == s2) {
      // fused QKV: N=1536; q/k -> head layout, v -> flat (all bf16)
      gemm(n1bf, 512, 0, wfull, 512, 0, bfull, nullptr, nullptr, qkvbf, 0, 0,
           2048, 1536, 512, 1.f, 0, 3, 0, 1);
    } else {
      ln(s2, nullptr, nullptr, sln_g + (size_t)i * 512, sln_b + (size_t)i * 512,
         nullptr, n2bf, 0, 0);
      gemm(n1bf, 512, 0, wfull, 512, 0, bfull, nullptr, nullptr, qkvbf, 0, 0,
           2048, 512, 512, 1.f, 0, 1, 0, 1);
      // fused KV: osec=1 -> k to sec1 (head), v to sec2 (flat)
      gemm(n2bf, 512, 0, wfull + 262144, 512, 0, bfull + 512, nullptr, nullptr,
           qkvbf, 0, 0, 2048, 1024, 512, 1.f, 0, 3, 1, 1);
    }
    to_heads_t<<<4096, 256, 0, stream>>>(vflatbf, vtbf);   // (B,H,hd,S)
    // scores[bh] = (1/8) * Qh @ Kh^T   (M=N=256, K=64, batch=64)
    gemm(qhbf, 64, 16384, khbf, 64, 16384, nullptr, nullptr, scoresF, nullptr,
         256, 65536, 256, 256, 64, 0.125f, 0, 0, 0, 64);
    softmax_rows<<<16384, 256, 0, stream>>>(scoresF, scoresBf);
    // ob(flat b,s,d) = P @ V  via TN with W=Vt (N=64,K=256), omode 2, bf16 out
    gemm(scoresBf, 256, 65536, vtbf, 256, 16384, nullptr, nullptr, nullptr,
         obbf, 512, 0, 256, 64, 256, 1.f, 0, 2, 0, 64);
    gemm(obbf, 512, 0, aoutwbf + (size_t)i * 262144, 512, 0,
         aout_b + (size_t)i * 512, s1, o_str, o_strbf, 512, 0,
         2048, 512, 512, 1.f, 0, 0, 0, 1);
  };

  auto ffn = [&](float* x, short* xbf, int i) {
    gemm(xbf, 512, 0, fw1bf + (size_t)i * 524288, 512, 0,
         f_b1 + (size_t)i * 1024, nullptr, nullptr, hbufbf, 1024, 0,
         2048, 1024, 512, 1.f, 2, 0, 0, 1);
    gemm(hbufbf, 1024, 0, fw2bf + (size_t)i * 524288, 1024, 0,
         f_b2 + (size_t)i * 512, nullptr, h2, nullptr, 512, 0,
         2048, 512, 1024, 1.f, 0, 0, 0, 1);
    ln(x, h2, nullptr, f_lng + (size_t)i * 512, f_lnb + (size_t)i * 512,
       x, xbf, 1, 0);
  };

  // ---- stems ----
  const float* ins[3] = {text, video, audio};
  for (int j = 0; j < 3; ++j) {
    cvt(ins[j], inbf, 2048 * 512);
    gemm(inbf, 512, 0, embbf, 512, 0, emb_b, nullptr, sb[j], nullptr, 512, 0,
         2048, 512, 512, 1.f, 0, 0, 0, 1);
    ln(sb[j], nullptr, nullptr, ada_a, ada_b, sb[j], sbbf[j], 1, 1);  // +PE
  }
  // ---- mamba 0..2 ----
  for (int j = 0; j < 3; ++j) mamba_layer(sb[j], sbbf[j], j);
  // ---- self attention 0..2 ----
  sub(sb[0], sb[0], 0, sb[3], sbbf[3]);
  sub(sb[1], sb[1], 1, sb[4], sbbf[4]);
  sub(sb[2], sb[2], 2, sb[5], sbbf[5]);
  // ---- cross attention 3..5 (t=sb3, v=sb4, a=sb5) ----
  sub(sb[3], sb[5], 3, sb[0], sbbf[0]);
  sub(sb[4], sb[3], 4, sb[1], sbbf[1]);
  sub(sb[5], sb[4], 5, sb[2], sbbf[2]);
  // ---- mamba 3..5 ----
  for (int j = 0; j < 3; ++j) mamba_layer(sb[j], sbbf[j], 3 + j);
  // ---- self attention 6..8 ----
  sub(sb[0], sb[0], 6, sb[3], sbbf[3]);
  sub(sb[1], sb[1], 7, sb[4], sbbf[4]);
  sub(sb[2], sb[2], 8, sb[5], sbbf[5]);
  // ---- ffn 0..2 ----
  for (int j = 0; j < 3; ++j) ffn(sb[3 + j], sbbf[3 + j], j);
  // ---- final norm: torch_ln(t+v+a) -> out ----
  ln(sb[3], sb[4], sb[5], n1_g, n1_b, outp, nullptr, 0, 0);
}

// Round 7
// 1319.079 us; speedup vs baseline: 4.1210x; 1.4437x over previous
//
#include <hip/hip_runtime.h>
#include <hip/hip_bf16.h>
#include <math.h>

// ---------------- constants ----------------
// B=8 S=256 D=512 H=8 hd=64 DI=1024 DS=16 DC=4 DTR=32 DF=1024
// rows = B*S = 2048, MF = 2048*512 = 1048576 elements per stream plane

using bf16x8 = __attribute__((ext_vector_type(8))) short;
using floatx16 = __attribute__((ext_vector_type(16))) float;

__device__ inline short f2bf(float x) {
  __hip_bfloat16 h = __float2bfloat16(x);
  return *reinterpret_cast<short*>(&h);
}

// ---------------- reduction helpers (blockDim == 256) ----------------
__device__ inline float wave_sum(float v) {
#pragma unroll
  for (int o = 32; o > 0; o >>= 1) v += __shfl_xor(v, o, 64);
  return v;
}
__device__ inline float wave_maxf(float v) {
#pragma unroll
  for (int o = 32; o > 0; o >>= 1) v = fmaxf(v, __shfl_xor(v, o, 64));
  return v;
}
__device__ inline float block_sum(float v, float* sm) {
  v = wave_sum(v);
  if ((threadIdx.x & 63) == 0) sm[threadIdx.x >> 6] = v;
  __syncthreads();
  float r = sm[0] + sm[1] + sm[2] + sm[3];
  __syncthreads();
  return r;
}
__device__ inline float block_max(float v, float* sm) {
  v = wave_maxf(v);
  if ((threadIdx.x & 63) == 0) sm[threadIdx.x >> 6] = v;
  __syncthreads();
  float r = fmaxf(fmaxf(sm[0], sm[1]), fmaxf(sm[2], sm[3]));
  __syncthreads();
  return r;
}

// ---------------- f32 -> bf16 elementwise (n multiple of 1024) ----------------
__global__ __launch_bounds__(256) void cvt_bf16(const float* __restrict__ in,
                                                short* __restrict__ out) {
  int i = (blockIdx.x * 256 + threadIdx.x) * 4;
  float4 v = *(const float4*)(in + i);
  short4 o;
  o.x = f2bf(v.x); o.y = f2bf(v.y); o.z = f2bf(v.z); o.w = f2bf(v.w);
  *(short4*)(out + i) = o;
}

// ---------------- bf16 MFMA GEMM, generalized batch --------------------------
// z decodes as zs = z/zdiv (outer/stream), zb = z%zdiv (inner, e.g. b*8+h).
// A += sA*zb + sAo*zs; same for W, C. bias += sBias*zs; res += sRes*zs.
// omode: 0 plain; 1 heads (b,s,h*64+c)->(b,h,s,c); 2 unheads (zb=b*8+h ->
// flat b,s,d); 3 qkv split (sec=(n>>9)+osec; 0/1 head layout, 2 flat).
__global__ __launch_bounds__(256) void gemm_bf16(
    const short* __restrict__ A, int lda, long long sA, long long sAo,
    const short* __restrict__ W, int ldw, long long sW, long long sWo,
    const float* __restrict__ bias, long long sBias,
    const float* __restrict__ res, long long sRes,
    float* __restrict__ C, short* __restrict__ Cbf, int ldc,
    long long sC, long long sCo,
    int K, float alpha, int act, int omode, int osec, int zdiv) {
  __shared__ short As[4 * 528];
  __shared__ short Bs[4 * 528];
  const int bz = blockIdx.z;
  const int zs = bz / zdiv, zb = bz % zdiv;
  A += sA * zb + sAo * zs;
  W += sW * zb + sWo * zs;
  if (C) C += sC * zb + sCo * zs;
  if (Cbf) Cbf += sC * zb + sCo * zs;
  const int m0 = blockIdx.y * 64, n0 = blockIdx.x * 64;
  const int tid = threadIdx.x, lane = tid & 63, wv = tid >> 6;
  const int mq = (wv & 1) * 32, nq = (wv >> 1) * 32;
  const int r31 = lane & 31, half = lane >> 5;
  const int mA = tid >> 2, kgA = tid & 3;   // staging: kg fast
  floatx16 acc = {};
  const short* pa = A + (long long)(m0 + mA) * lda + kgA * 8;
  const short* pb = W + (long long)(n0 + mA) * ldw + kgA * 8;
  short* wa = As + kgA * 528 + mA * 8;
  short* wb = Bs + kgA * 528 + mA * 8;
  const short* ra = As + (mq + r31) * 8 + half * 528;
  const short* rb = Bs + (nq + r31) * 8 + half * 528;
  bf16x8 av = *(const bf16x8*)pa;
  bf16x8 bv = *(const bf16x8*)pb;
  for (int k0 = 0; k0 < K; k0 += 32) {
    __syncthreads();  // previous iter's frag reads done
    *(bf16x8*)wa = av;
    *(bf16x8*)wb = bv;
    __syncthreads();
    if (k0 + 32 < K) {  // prefetch next slab, overlapped with MFMAs
      av = *(const bf16x8*)(pa + k0 + 32);
      bv = *(const bf16x8*)(pb + k0 + 32);
    }
    acc = __builtin_amdgcn_mfma_f32_32x32x16_bf16(
        *(const bf16x8*)ra, *(const bf16x8*)rb, acc, 0, 0, 0);
    acc = __builtin_amdgcn_mfma_f32_32x32x16_bf16(
        *(const bf16x8*)(ra + 2 * 528), *(const bf16x8*)(rb + 2 * 528), acc, 0, 0, 0);
  }
  const int n = n0 + nq + r31;
  const float bvb = bias ? bias[sBias * zs + n] : 0.f;
#pragma unroll
  for (int r = 0; r < 16; ++r) {
    const int m = m0 + mq + (r & 3) + 8 * (r >> 2) + 4 * half;
    float v = acc[r] * alpha + bvb;
    if (act == 1) v = fmaxf(v, 0.f) + log1pf(expf(-fabsf(v)));
    else if (act == 2) v = fmaxf(v, 0.f);
    if (res) v += res[sRes * zs + (long long)m * ldc + n];
    long long idx;
    if (omode == 0) idx = (long long)m * ldc + n;
    else if (omode == 1)
      idx = (long long)(m >> 8) * 131072 + (long long)(n >> 6) * 16384 +
            (m & 255) * 64 + (n & 63);
    else if (omode == 2)
      idx = (long long)(zb >> 3) * 131072 + (zb & 7) * 64 +
            (long long)m * 512 + n;
    else {
      const int sec = (n >> 9) + osec;
      const int d = n & 511;
      if (sec < 2)
        idx = (long long)sec * 1048576 +
              (((long long)(m >> 8) * 8 + (d >> 6)) * 256 + (m & 255)) * 64 +
              (d & 63);
      else
        idx = 2LL * 1048576 + (long long)m * 512 + d;
    }
    if (C) C[idx] = v;
    if (Cbf) Cbf[idx] = f2bf(v);
  }
}

// ---------------- LayerNorm, stream-batched (2048 rows/stream) ----------------
// mode 0: torch_ln; mode 1: custom_ln/adaln. stream = blockIdx.x>>11.
__device__ inline float pe_val(int bi, int c) {
  float f = expf((float)(c & ~1) * (-9.210340371976184f / 512.f));
  float arg = (float)bi * f;
  return (c & 1) ? cosf(arg) : sinf(arg);
}
__global__ __launch_bounds__(256) void ln_kernel(
    const float* __restrict__ in1, long long s1,
    const float* __restrict__ in2, long long s2,
    const float* __restrict__ in3,
    const float* __restrict__ g, const float* __restrict__ bb, long long sg,
    float* __restrict__ out, short* __restrict__ obf, long long so,
    int mode, int add_pe) {
  __shared__ float sm[4];
  const int row = blockIdx.x, tid = threadIdx.x;
  const int stream = row >> 11, lr = row & 2047;
  in1 += stream * s1;
  if (in2) in2 += stream * s2;
  g += stream * sg; bb += stream * sg;
  const long long base = (long long)lr * 512;
  const long long obase = stream * so + base;
  float x0 = in1[base + tid];
  float x1 = in1[base + tid + 256];
  if (in2) { x0 += in2[base + tid]; x1 += in2[base + tid + 256]; }
  if (in3) { x0 += in3[base + tid]; x1 += in3[base + tid + 256]; }
  if (add_pe) {
    int bi = lr >> 8;
    x0 += pe_val(bi, tid);
    x1 += pe_val(bi, tid + 256);
  }
  float m = block_sum(x0 + x1, sm) * (1.f / 512.f);
  float d0 = x0 - m, d1 = x1 - m;
  float ss = block_sum(d0 * d0 + d1 * d1, sm);
  float r0, r1;
  if (mode == 0) {
    float rstd = rsqrtf(ss * (1.f / 512.f) + 1e-5f);
    r0 = d0 * rstd * g[tid] + bb[tid];
    r1 = d1 * rstd * g[tid + 256] + bb[tid + 256];
  } else {
    float s = sqrtf(ss * (1.f / 511.f));
    float inv = 1.f / (s + 1e-6f);
    r0 = g[tid] * d0 * inv + bb[tid];
    r1 = g[tid + 256] * d1 * inv + bb[tid + 256];
  }
  if (out) { out[obase + tid] = r0; out[obase + tid + 256] = r1; }
  if (obf) { obf[obase + tid] = f2bf(r0); obf[obase + tid + 256] = f2bf(r1); }
}

// ---------------- causal depthwise conv + SiLU, 3-layer batched ----------------
__global__ __launch_bounds__(256) void conv_silu(
    const float* __restrict__ xz, const float* __restrict__ cw,
    const float* __restrict__ cb, float* __restrict__ u2,
    short* __restrict__ u2bf) {
  int gid = blockIdx.x * 256 + threadIdx.x;   // 0 .. 3*2M
  int lay = gid >> 21;
  int idx = gid & 2097151;                    // b*S*DI + t*DI + c
  int c = idx & 1023, t = (idx >> 10) & 255, b = idx >> 18;
  const float* base = xz + (long long)lay * 4194304 + (long long)b * 256 * 2048;
  cw += lay * 4096; cb += lay * 1024;
  float acc = cb[c];
#pragma unroll
  for (int k = 0; k < 4; ++k) {
    int tt = t + k - 3;
    if (tt >= 0) acc += base[tt * 2048 + c] * cw[c * 4 + k];
  }
  float v = acc / (1.f + expf(-acc));
  u2[gid] = v;
  u2bf[gid] = f2bf(v);
}

// ---------------- selective-scan, single-buffer LDS + reg prefetch ----------
// grid (64, 24): lay = blockIdx.y>>3, b = blockIdx.y&7. 24.5 KB LDS ->
// 6 blocks/CU; TLP hides the load phase across resident blocks.
__global__ __launch_bounds__(256) void scan_kernel(
    const float* __restrict__ delta, const float* __restrict__ u2,
    const float* __restrict__ xz, const float* __restrict__ xdbl,
    const float* __restrict__ Alog, const float* __restrict__ Dp,
    short* __restrict__ ys) {
  __shared__ float sdel[64][16];
  __shared__ float su[64][16];
  __shared__ float sz[64][16];
  __shared__ float sxd[64][32];
  __shared__ float sy[64][16];
  const int lay = blockIdx.y >> 3, b = blockIdx.y & 7;
  delta += (long long)lay * 2097152;
  u2 += (long long)lay * 2097152;
  xz += (long long)lay * 4194304;
  xdbl += (long long)lay * 131072;
  Alog += lay * 16384;
  Dp += lay * 1024;
  ys += (long long)lay * 2097152;
  const int tid = threadIdx.x;
  const int lane = tid & 63;
  const int wv = tid >> 6;
  const int s = lane >> 2;
  const int dsub = lane & 3;
  const int dl = wv * 4 + dsub;
  const int d0 = blockIdx.x * 16;
  const int d = d0 + dl;
  const float A = -expf(Alog[d * 16 + s]);
  const float Dd = Dp[d];
  const long long rowbase = (long long)b * 256;
  float rdel[4], ru[4], rz[4], rxd[8];
  auto issue = [&](int c) {
    const int t0 = c * 64;
#pragma unroll
    for (int k = 0; k < 4; ++k) {
      int e = k * 256 + tid;
      int t = e >> 4, dd = e & 15;
      long long r = rowbase + t0 + t;
      rdel[k] = delta[r * 1024 + d0 + dd];
      ru[k]   = u2[r * 1024 + d0 + dd];
      rz[k]   = xz[r * 2048 + 1024 + d0 + dd];
    }
#pragma unroll
    for (int k = 0; k < 8; ++k) {
      int e = k * 256 + tid;
      int t = e >> 5, j = e & 31;
      rxd[k] = xdbl[(rowbase + t0 + t) * 64 + 32 + j];
    }
  };
  auto commit = [&]() {
#pragma unroll
    for (int k = 0; k < 4; ++k) {
      int e = k * 256 + tid;
      int t = e >> 4, dd = e & 15;
      sdel[t][dd] = rdel[k]; su[t][dd] = ru[k]; sz[t][dd] = rz[k];
    }
#pragma unroll
    for (int k = 0; k < 8; ++k) {
      int e = k * 256 + tid;
      int t = e >> 5, j = e & 31;
      sxd[t][j] = rxd[k];
    }
  };
  issue(0);
  commit();
  float h = 0.f;
  for (int c = 0; c < 4; ++c) {
    __syncthreads();                 // buffer ready for all waves
    if (c < 3) issue(c + 1);         // next chunk's loads overlap compute
#pragma unroll 4
    for (int t = 0; t < 64; ++t) {
      const float dt = sdel[t][dl];
      const float uu = su[t][dl];
      const float Bs = sxd[t][s];
      const float Cs = sxd[t][16 + s];
      h = __expf(dt * A) * h + dt * uu * Bs;
      float pp = h * Cs;
      pp += __shfl_xor(pp, 4, 64);
      pp += __shfl_xor(pp, 8, 64);
      pp += __shfl_xor(pp, 16, 64);
      pp += __shfl_xor(pp, 32, 64);
      if (s == 0) {
        const float zz = sz[t][dl];
        sy[t][dl] = (pp + Dd * uu) * (zz / (1.f + expf(-zz)));
      }
    }
    __syncthreads();                 // compute reads done; sy complete
    const int t0 = c * 64;
#pragma unroll
    for (int k = 0; k < 4; ++k) {
      int e = k * 256 + tid;
      int t = e >> 4, dd = e & 15;
      ys[(rowbase + t0 + t) * 1024 + d0 + dd] = f2bf(sy[t][dd]);
    }
    if (c < 3) commit();
  }
}

// ---------------- softmax rows of 256: f32 in -> bf16 out ----------------
__global__ __launch_bounds__(256) void softmax_rows(const float* __restrict__ S,
                                                    short* __restrict__ Sbf) {
  __shared__ float sm[4];
  const float* p = S + (long long)blockIdx.x * 256;
  float v = p[threadIdx.x];
  float m = block_max(v, sm);
  float e = expf(v - m);
  float s = block_sum(e, sm);
  Sbf[(long long)blockIdx.x * 256 + threadIdx.x] = f2bf(e / s);
}

// ---------------- V transpose (bf16, 3 streams): -> (B,H,hd,S) ----------------
__global__ __launch_bounds__(256) void to_heads_t(const short* __restrict__ in,
                                                  short* __restrict__ out) {
  int e = blockIdx.x * 256 + threadIdx.x;
  int stream = e >> 20;
  int inner = e & 1048575;
  int s = inner & 255, c = (inner >> 8) & 63, h = (inner >> 14) & 7, b = inner >> 17;
  out[(long long)stream * 1048576 + inner] =
      in[(long long)stream * 3145728 + 2097152 + ((b * 256 + s) * 512) + h * 64 + c];
}

// ---------------- host orchestration ----------------
extern "C" void kernel_launch(void* const* d_in, const int* in_sizes, int n_in,
                              void* d_out, int out_size, void* d_ws, size_t ws_size,
                              hipStream_t stream) {
  (void)in_sizes; (void)n_in; (void)out_size; (void)ws_size;
  const float* text   = (const float*)d_in[0];
  const float* video  = (const float*)d_in[1];
  const float* audio  = (const float*)d_in[2];
  const float* emb_w  = (const float*)d_in[3];
  const float* emb_b  = (const float*)d_in[4];
  const float* ada_a  = (const float*)d_in[5];
  const float* ada_b  = (const float*)d_in[6];
  const float* m_in_w = (const float*)d_in[7];
  const float* m_cw   = (const float*)d_in[8];
  const float* m_cb   = (const float*)d_in[9];
  const float* m_xp   = (const float*)d_in[10];
  const float* m_dtw  = (const float*)d_in[11];
  const float* m_dtb  = (const float*)d_in[12];
  const float* m_Alog = (const float*)d_in[13];
  const float* m_Dp   = (const float*)d_in[14];
  const float* m_ow   = (const float*)d_in[15];
  const float* m_lng  = (const float*)d_in[16];
  const float* m_lnb  = (const float*)d_in[17];
  const float* qkv_w  = (const float*)d_in[18];
  const float* qkv_b  = (const float*)d_in[19];
  const float* aout_w = (const float*)d_in[20];
  const float* aout_b = (const float*)d_in[21];
  const float* sln_g  = (const float*)d_in[22];
  const float* sln_b  = (const float*)d_in[23];
  const float* f_w1   = (const float*)d_in[24];
  const float* f_b1   = (const float*)d_in[25];
  const float* f_w2   = (const float*)d_in[26];
  const float* f_b2   = (const float*)d_in[27];
  const float* f_lng  = (const float*)d_in[28];
  const float* f_lnb  = (const float*)d_in[29];
  const float* n1_g   = (const float*)d_in[30];
  const float* n1_b   = (const float*)d_in[31];
  float* outp = (float*)d_out;

  const long long MF = 1048576;   // 2048*512

  // ---------- workspace arenas (units = floats; bf16 arenas cast) ----------
  float* ws = (float*)d_ws;
  size_t off = 0;
  auto alloc = [&](size_t n) { float* p = ws + off; off += n; return p; };
  auto allocs = [&](size_t n_bf16) { return (short*)alloc((n_bf16 + 1) / 2); };
  float* sb0    = alloc(6 * MF);            // sb[j] = sb0 + j*MF
  short* sbbf0  = allocs(6 * MF);
  short* inbf   = allocs(3 * MF);
  float* xzA    = alloc(3 * 4194304);       // xz | scoresF
  float* u2A    = alloc(3 * 2097152);       // u2 f32 | scoresBf
  float* dlA    = alloc(3 * 2097152);       // dl f32 | qkvA (9M shorts)
  short* ysA    = allocs(3 * 2097152);      // ys bf16 | vtA+obA
  float* xdblA  = alloc(3 * 131072);
  short* xdblbfA= allocs(3 * 131072);
  float* mtmpA  = alloc(3 * MF);            // mtmp | h2
  short* u2bfA  = allocs(3 * 2097152);      // u2bf | hbufbf
  short* n1bfA  = allocs(3 * MF);
  short* n2bfA  = allocs(3 * MF);
  // bf16 weights
  short* embbf   = allocs(512 * 512);
  short* minbf   = allocs(6 * 1048576);
  short* mxpbf   = allocs(6 * 65536);
  short* mdtwbf  = allocs(6 * 32768);
  short* mowbf   = allocs(6 * 524288);
  short* qkvwbf  = allocs(9 * 786432);
  short* aoutwbf = allocs(9 * 262144);
  short* fw1bf   = allocs(3 * 524288);
  short* fw2bf   = allocs(3 * 524288);

  float* scoresF  = xzA;
  short* scoresBf = (short*)u2A;
  short* qkvA     = (short*)dlA;            // per stream: q|k|v (3M shorts)
  short* vtA      = ysA;                    // 3 x 1M
  short* obA      = ysA + 3145728;          // 3 x 1M
  short* hbufbfA  = u2bfA;
  float* h2A      = mtmpA;

  auto cvt = [&](const float* in, short* out, int n) {
    cvt_bf16<<<n / 1024, 256, 0, stream>>>(in, out);
  };
  auto gemm = [&](const short* A, int lda, long long sA, long long sAo,
                  const short* W, int ldw, long long sW, long long sWo,
                  const float* bias, long long sB,
                  const float* res, long long sR,
                  float* C, short* Cbf, int ldc, long long sC, long long sCo,
                  int M, int N, int K, float alpha, int act,
                  int omode, int osec, int zdiv, int batch) {
    dim3 g(N / 64, M / 64, batch);
    gemm_bf16<<<g, 256, 0, stream>>>(A, lda, sA, sAo, W, ldw, sW, sWo,
                                     bias, sB, res, sR, C, Cbf, ldc, sC, sCo,
                                     K, alpha, act, omode, osec, zdiv);
  };
  auto ln = [&](const float* i1, long long s1, const float* i2, long long s2,
                const float* i3, const float* g, const float* b, long long sg,
                float* o, short* obf, long long so, int mode, int pe,
                int nblocks) {
    ln_kernel<<<nblocks, 256, 0, stream>>>(i1, s1, i2, s2, i3, g, b, sg,
                                           o, obf, so, mode, pe);
  };

  // ---- pre-convert all weights to bf16 ----
  cvt(emb_w,  embbf,   512 * 512);
  cvt(m_in_w, minbf,   6 * 1048576);
  cvt(m_xp,   mxpbf,   6 * 65536);
  cvt(m_dtw,  mdtwbf,  6 * 32768);
  cvt(m_ow,   mowbf,   6 * 524288);
  cvt(qkv_w,  qkvwbf,  9 * 786432);
  cvt(aout_w, aoutwbf, 9 * 262144);
  cvt(f_w1,   fw1bf,   3 * 524288);
  cvt(f_w2,   fw2bf,   3 * 524288);

  // ---- mamba group (layers g0..g0+2 on sb[0..2]) ----
  auto mamba3 = [&](int g0) {
    gemm(sbbf0, 512, 0, MF,  minbf + (size_t)g0 * 1048576, 512, 0, 1048576,
         nullptr, 0, nullptr, 0,  xzA, nullptr, 2048, 0, 4194304,
         2048, 2048, 512, 1.f, 0, 0, 0, 1, 3);
    conv_silu<<<24576, 256, 0, stream>>>(xzA, m_cw + (size_t)g0 * 4096,
                                         m_cb + (size_t)g0 * 1024, u2A, u2bfA);
    gemm(u2bfA, 1024, 0, 2097152,  mxpbf + (size_t)g0 * 65536, 1024, 0, 65536,
         nullptr, 0, nullptr, 0,  xdblA, xdblbfA, 64, 0, 131072,
         2048, 64, 1024, 1.f, 0, 0, 0, 1, 3);
    gemm(xdblbfA, 64, 0, 131072,  mdtwbf + (size_t)g0 * 32768, 32, 0, 32768,
         m_dtb + (size_t)g0 * 1024, 1024, nullptr, 0,
         dlA, nullptr, 1024, 0, 2097152,
         2048, 1024, 32, 1.f, 1, 0, 0, 1, 3);
    scan_kernel<<<dim3(64, 24), 256, 0, stream>>>(
        dlA, u2A, xzA, xdblA, m_Alog + (size_t)g0 * 16384,
        m_Dp + (size_t)g0 * 1024, ysA);
    gemm(ysA, 1024, 0, 2097152,  mowbf + (size_t)g0 * 524288, 1024, 0, 524288,
         nullptr, 0, nullptr, 0,  mtmpA, nullptr, 512, 0, MF,
         2048, 512, 1024, 1.f, 0, 0, 0, 1, 3);
    ln(sb0, MF, mtmpA, MF, nullptr, m_lng + (size_t)g0 * 512,
       m_lnb + (size_t)g0 * 512, 512, sb0, sbbf0, MF, 0, 0, 6144);
  };

  // ---- attention core (after q/k/v in qkvA) ----
  auto attn_core = [&](int i0, const float* s1b, float* outb, short* outbfb) {
    to_heads_t<<<12288, 256, 0, stream>>>(qkvA, vtA);
    gemm(qkvA, 64, 16384, 3 * MF,  qkvA + MF, 64, 16384, 3 * MF,
         nullptr, 0, nullptr, 0,  scoresF, nullptr, 256, 65536, 4194304,
         256, 256, 64, 0.125f, 0, 0, 0, 64, 192);
    softmax_rows<<<49152, 256, 0, stream>>>(scoresF, scoresBf);
    gemm(scoresBf, 256, 65536, 4194304,  vtA, 256, 16384, MF,
         nullptr, 0, nullptr, 0,  nullptr, obA, 512, 0, MF,
         256, 64, 256, 1.f, 0, 2, 0, 64, 192);
    gemm(obA, 512, 0, MF,  aoutwbf + (size_t)i0 * 262144, 512, 0, 262144,
         aout_b + (size_t)i0 * 512, 512,  s1b, MF,
         outb, outbfb, 512, 0, MF,
         2048, 512, 512, 1.f, 0, 0, 0, 1, 3);
  };

  auto attn_self = [&](int i0, const float* s1b, float* outb, short* outbfb) {
    ln(s1b, MF, nullptr, 0, nullptr, sln_g + (size_t)i0 * 512,
       sln_b + (size_t)i0 * 512, 512, nullptr, n1bfA, MF, 0, 0, 6144);
    gemm(n1bfA, 512, 0, MF,  qkvwbf + (size_t)i0 * 786432, 512, 0, 786432,
         qkv_b + (size_t)i0 * 1536, 1536, nullptr, 0,
         nullptr, qkvA, 0, 0, 3 * MF,
         2048, 1536, 512, 1.f, 0, 3, 0, 1, 3);
    attn_core(i0, s1b, outb, outbfb);
  };

  auto attn_cross = [&](int i0, const float* s1b, const float* s2p0,
                        const float* s2p1, const float* s2p2,
                        float* outb, short* outbfb) {
    ln(s1b, MF, nullptr, 0, nullptr, sln_g + (size_t)i0 * 512,
       sln_b + (size_t)i0 * 512, 512, nullptr, n1bfA, MF, 0, 0, 6144);
    const float* s2p[3] = {s2p0, s2p1, s2p2};
    for (int s = 0; s < 3; ++s)
      ln(s2p[s], 0, nullptr, 0, nullptr, sln_g + (size_t)(i0 + s) * 512,
         sln_b + (size_t)(i0 + s) * 512, 0, nullptr, n2bfA + s * MF, 0,
         0, 0, 2048);
    gemm(n1bfA, 512, 0, MF,  qkvwbf + (size_t)i0 * 786432, 512, 0, 786432,
         qkv_b + (size_t)i0 * 1536, 1536, nullptr, 0,
         nullptr, qkvA, 0, 0, 3 * MF,
         2048, 512, 512, 1.f, 0, 1, 0, 1, 3);
    gemm(n2bfA, 512, 0, MF,  qkvwbf + (size_t)i0 * 786432 + 262144, 512, 0, 786432,
         qkv_b + (size_t)i0 * 1536 + 512, 1536, nullptr, 0,
         nullptr, qkvA, 0, 0, 3 * MF,
         2048, 1024, 512, 1.f, 0, 3, 1, 1, 3);
    attn_core(i0, s1b, outb, outbfb);
  };

  // ---- stems ----
  const float* ins[3] = {text, video, audio};
  for (int j = 0; j < 3; ++j) cvt(ins[j], inbf + j * MF, MF);
  gemm(inbf, 512, 0, MF,  embbf, 512, 0, 0,  emb_b, 0, nullptr, 0,
       sb0, nullptr, 512, 0, MF, 2048, 512, 512, 1.f, 0, 0, 0, 1, 3);
  ln(sb0, MF, nullptr, 0, nullptr, ada_a, ada_b, 0, sb0, sbbf0, MF, 1, 1, 6144);
  // ---- mamba 0..2 ----
  mamba3(0);
  // ---- self attention 0..2: sb[0..2] -> sb[3..5] ----
  attn_self(0, sb0, sb0 + 3 * MF, nullptr);
  // ---- cross attention 3..5: (t,v,a)=sb[3..5], s2=(a,t,v) -> sb[0..2] ----
  attn_cross(3, sb0 + 3 * MF, sb0 + 5 * MF, sb0 + 3 * MF, sb0 + 4 * MF,
             sb0, sbbf0);
  // ---- mamba 3..5 ----
  mamba3(3);
  // ---- self attention 6..8: sb[0..2] -> sb[3..5] ----
  attn_self(6, sb0, sb0 + 3 * MF, sbbf0 + 3 * MF);
  // ---- ffn 0..2 on sb[3..5] ----
  gemm(sbbf0 + 3 * MF, 512, 0, MF,  fw1bf, 512, 0, 524288,
       f_b1, 1024, nullptr, 0,  nullptr, hbufbfA, 1024, 0, 2097152,
       2048, 1024, 512, 1.f, 2, 0, 0, 1, 3);
  gemm(hbufbfA, 1024, 0, 2097152,  fw2bf, 1024, 0, 524288,
       f_b2, 512, nullptr, 0,  h2A, nullptr, 512, 0, MF,
       2048, 512, 1024, 1.f, 0, 0, 0, 1, 3);
  ln(sb0 + 3 * MF, MF, h2A, MF, nullptr, f_lng, f_lnb, 512,
     sb0 + 3 * MF, nullptr, MF, 1, 0, 6144);
  // ---- final norm: torch_ln(t+v+a) -> out ----
  ln(sb0 + 3 * MF, 0, sb0 + 4 * MF, 0, sb0 + 5 * MF, n1_g, n1_b, 0,
     outp, nullptr, 0, 0, 0, 2048);
}